// Round 5
// baseline (11216.309 us; speedup 1.0000x reference)
//
#include <hip/hip_runtime.h>

#define Bz   32
#define Sz   64
#define Tdec 63
#define Ez   256
#define Hz   512
#define H3z  1536
#define Vz   32000
#define NB   128   // persistent grid blocks

typedef __attribute__((ext_vector_type(4))) float f32x4;
typedef __attribute__((ext_vector_type(4))) float floatx4;
typedef __attribute__((ext_vector_type(8))) short shortx8;

__device__ __forceinline__ unsigned short f2bf(float f) {
  unsigned x = __float_as_uint(f);
  unsigned r = (x + 0x7fffu + ((x >> 16) & 1u)) >> 16;
  return (unsigned short)r;
}

// ======== sc0/sc1 (MALL-coherent, L1/L2-bypass) access helpers ========
__device__ __forceinline__ f32x4 ld_sc_nw(const f32x4* p) {  // no wait
  f32x4 r;
  asm volatile("global_load_dwordx4 %0, %1, off sc0 sc1" : "=&v"(r) : "v"(p));
  return r;
}
__device__ __forceinline__ void wait_vm0() {
  asm volatile("s_waitcnt vmcnt(0)" ::: "memory");
}
__device__ __forceinline__ void ld2f_sc(const float* p0, const float* p1,
                                        float& a, float& b) {
  asm volatile(
      "global_load_dword %0, %2, off sc0 sc1\n\t"
      "global_load_dword %1, %3, off sc0 sc1\n\t"
      "s_waitcnt vmcnt(0)"
      : "=&v"(a), "=&v"(b) : "v"(p0), "v"(p1) : "memory");
}
__device__ __forceinline__ void st_sc(float* p, float v) {
  asm volatile("global_store_dword %0, %1, off sc0 sc1" :: "v"(p), "v"(v) : "memory");
}
__device__ __forceinline__ void st_flag(unsigned* p, unsigned v) {
  asm volatile("global_store_dword %0, %1, off sc0 sc1" :: "v"(p), "v"(v) : "memory");
}
__device__ __forceinline__ void ld2u_sc(const unsigned* p0, const unsigned* p1,
                                        unsigned& a, unsigned& b) {
  asm volatile(
      "global_load_dword %0, %2, off sc0 sc1\n\t"
      "global_load_dword %1, %3, off sc0 sc1\n\t"
      "s_waitcnt vmcnt(0)"
      : "=&v"(a), "=&v"(b) : "v"(p0), "v"(p1) : "memory");
}

// ---------------- generic transpose: out[c][r] = in[r][c0+c] ----------------
__global__ __launch_bounds__(256)
void k_transpose(const float* __restrict__ in, int R, int Ctot, int c0,
                 float* __restrict__ out) {
  __shared__ float tile[32][33];
  int ct = blockIdx.x * 32;
  int rt = blockIdx.y * 32;
  int lx = threadIdx.x & 31, ly = threadIdx.x >> 5;
#pragma unroll
  for (int i = 0; i < 32; i += 8)
    tile[ly + i][lx] = in[(long)(rt + ly + i) * Ctot + c0 + ct + lx];
  __syncthreads();
#pragma unroll
  for (int i = 0; i < 32; i += 8)
    out[(long)(ct + ly + i) * R + rt + lx] = tile[lx][ly + i];
}

// ---- pack weights: out[(k4+k4off)*1536*4 + j*4 + q] = in[j*rs + c0 + k4*4+q]
__global__ __launch_bounds__(256)
void k_pack4(const float* __restrict__ in, int rs, int c0,
             float* __restrict__ out, int k4off) {
  int jl = threadIdx.x & 15, k4l = threadIdx.x >> 4;
  int j = blockIdx.y * 16 + jl;
  int k4 = blockIdx.x * 16 + k4l;
  float4 v = *(const float4*)(in + (long)j * rs + c0 + k4 * 4);
  *(float4*)(out + ((long)(k4 + k4off) * H3z + j) * 4) = v;
}

// -------- embed + input-GEMM with packed weights W4[k4][1536][4], K=256
__global__ __launch_bounds__(256)
void k_embed_gi(const int* __restrict__ toks, const float* __restrict__ emb,
                const float* __restrict__ W4, const float* __restrict__ bias,
                float* __restrict__ G) {
  __shared__ float se[16][Ez];
  int jg = blockIdx.x % 24;
  int rg = blockIdx.x / 24;
  int r0 = rg * 16;
  int tid = threadIdx.x;
  for (int c = tid; c < 16 * Ez; c += 256) {
    int rl = c >> 8;
    int k = c & 255;
    int r = r0 + rl;
    int tok = toks[(r & 31) * 64 + (r >> 5)];
    se[rl][k] = emb[(long)tok * Ez + k];
  }
  __syncthreads();
  int jj = tid & 63, rq = tid >> 6;
  int j = jg * 64 + jj;
  float a0 = 0.f, a1 = 0.f, a2 = 0.f, a3 = 0.f;
#pragma unroll 4
  for (int k4 = 0; k4 < 64; ++k4) {
    float4 w = *(const float4*)(W4 + ((long)k4 * H3z + j) * 4);
    const float* s0 = &se[rq * 4 + 0][k4 * 4];
    const float* s1 = &se[rq * 4 + 1][k4 * 4];
    const float* s2 = &se[rq * 4 + 2][k4 * 4];
    const float* s3 = &se[rq * 4 + 3][k4 * 4];
    a0 = fmaf(s0[3], w.w, fmaf(s0[2], w.z, fmaf(s0[1], w.y, fmaf(s0[0], w.x, a0))));
    a1 = fmaf(s1[3], w.w, fmaf(s1[2], w.z, fmaf(s1[1], w.y, fmaf(s1[0], w.x, a1))));
    a2 = fmaf(s2[3], w.w, fmaf(s2[2], w.z, fmaf(s2[1], w.y, fmaf(s2[0], w.x, a2))));
    a3 = fmaf(s3[3], w.w, fmaf(s3[2], w.z, fmaf(s3[1], w.y, fmaf(s3[0], w.x, a3))));
  }
  float bj = bias[j];
  G[(long)(r0 + rq * 4 + 0) * H3z + j] = a0 + bj;
  G[(long)(r0 + rq * 4 + 1) * H3z + j] = a1 + bj;
  G[(long)(r0 + rq * 4 + 2) * H3z + j] = a2 + bj;
  G[(long)(r0 + rq * 4 + 3) * H3z + j] = a3 + bj;
}

// ---------------- fp32 -> bf16 convert ----------------
__global__ void k_f2bf(const float* __restrict__ in, unsigned short* __restrict__ out, long n4) {
  long i = (long)blockIdx.x * blockDim.x + threadIdx.x;
  long stride = (long)gridDim.x * blockDim.x;
  for (; i < n4; i += stride) {
    float4 v = ((const float4*)in)[i];
    ushort4 o;
    o.x = f2bf(v.x); o.y = f2bf(v.y); o.z = f2bf(v.z); o.w = f2bf(v.w);
    ((ushort4*)out)[i] = o;
  }
}

// ================= persistent recurrence kernel =================
struct PP {
  const float* giEnc;
  const float* giDec;
  const float* W4e0;
  const float* W4e1;
  const float* W4d0;
  const float* W4d1;
  const float* enc_bhh0;
  const float* enc_bih1;
  const float* enc_bhh1;
  const float* dec_bhh0;
  const float* dec_bih1;
  const float* dec_bhh1;
  const float* wtAttn;
  const int* src;
  float* h0; float* h1; float* d0; float* d1; float* ctx;
  float* encOut;   // sc-space [32][64][512]
  float* encN;     // normal-cached copy, XCD-local to attn readers
  float* keN;      // normal-cached, XCD-local to attn readers
  unsigned short* d1ctxBf;
  unsigned* flags;   // [NB], monotone phase counters
};

// Grid barrier: drain sc stores (vmcnt), publish flag (sc), spin on sc flags.
// No L2 writeback/invalidate anywhere.
__device__ __forceinline__ void gsync(unsigned* flags, unsigned ph) {
  wait_vm0();
  __syncthreads();
  int tid = threadIdx.x;
  if (tid == 0) st_flag(&flags[blockIdx.x], ph);
  if (tid < 64) {
    const unsigned* p0 = &flags[tid];
    const unsigned* p1 = &flags[tid + 64];
    for (;;) {
      unsigned f0, f1;
      ld2u_sc(p0, p1, f0, f1);
      if (!__any(f0 < ph || f1 < ph)) break;
      __builtin_amdgcn_s_sleep(1);
    }
  }
  __syncthreads();
}

// GRU cell over 64 blocks: jg=blkid&7 (== XCD id -> weights L2-resident),
// bg=blkid>>3 (4 batch rows). Wave kq owns K-quarter kq.
// Weight loop: double-buffered 8x3 f32x4 register groups (24 loads in flight).
template <int HASX>
__device__ __forceinline__ void gru_cell(
    int blkid, const float* __restrict__ W4,
    const float* __restrict__ gi, const float* __restrict__ bih,
    const float* __restrict__ bhh,
    const float* __restrict__ xin, const float* __restrict__ hin,
    float* __restrict__ hout, float* __restrict__ fout, long fstride,
    unsigned short* __restrict__ bfout, float* smem) {
  float* sh = smem;            // [4][512]
  float* sx = smem + 2048;     // [4][512]
  float* part = smem + 4096;   // [3][4][4][64]
  const int jg = blkid & 7, bg = blkid >> 3;
  const int tid = threadIdx.x;
  const int l = tid & 63;
  const int kq = tid >> 6;
  const int j = jg * 64 + l;
  constexpr int Q = HASX ? 64 : 32;   // k4 per wave-quarter
  constexpr int G = Q / 8;            // 8-k4 groups
  const f32x4* Wr0 = (const f32x4*)W4 + (long)(kq * Q) * H3z + j;

  f32x4 wA[8][3], wB[8][3];
  // group-0 weight prefetch: issued before staging waits (independent of h)
  {
    const f32x4* Wr = Wr0;
#pragma unroll
    for (int u = 0; u < 8; ++u) {
      wA[u][0] = Wr[0]; wA[u][1] = Wr[512]; wA[u][2] = Wr[1024];
      Wr += H3z;
    }
  }
  // gi/bih prefetch for the combine stage (mapping: b4=tid>>6, jc=tid&63)
  float gir = 0.f, giz = 0.f, gin = 0.f;
  {
    const int b4 = tid >> 6, jc = tid & 63;
    const int b = bg * 4 + b4, jj = jg * 64 + jc;
    if (gi) {
      gir = gi[(long)b * H3z + jj];
      giz = gi[(long)b * H3z + 512 + jj];
      gin = gi[(long)b * H3z + 1024 + jj];
    }
    if (bih) { gir += bih[jj]; giz += bih[512 + jj]; gin += bih[1024 + jj]; }
  }
  // stage h (and x) via sc loads
  {
    const f32x4* hp = (const f32x4*)(hin + bg * 2048);
    if (HASX) {
      const f32x4* xp = (const f32x4*)(xin + bg * 2048);
      f32x4 a = ld_sc_nw(hp + tid);
      f32x4 b = ld_sc_nw(hp + tid + 256);
      f32x4 c = ld_sc_nw(xp + tid);
      f32x4 d = ld_sc_nw(xp + tid + 256);
      wait_vm0();
      ((f32x4*)sh)[tid] = a; ((f32x4*)sh)[tid + 256] = b;
      ((f32x4*)sx)[tid] = c; ((f32x4*)sx)[tid + 256] = d;
    } else {
      f32x4 a = ld_sc_nw(hp + tid);
      f32x4 b = ld_sc_nw(hp + tid + 256);
      wait_vm0();
      ((f32x4*)sh)[tid] = a; ((f32x4*)sh)[tid + 256] = b;
    }
  }
  __syncthreads();

  const f32x4* vb4;
  if (HASX) vb4 = (const f32x4*)((kq < 2) ? (sx + kq * 256) : (sh + (kq - 2) * 256));
  else      vb4 = (const f32x4*)(sh + kq * 128);
  float pr[4] = {0, 0, 0, 0}, pz[4] = {0, 0, 0, 0}, pn[4] = {0, 0, 0, 0};

  auto loadg = [&](f32x4 (&w)[8][3], int g) {
    const f32x4* Wr = Wr0 + (long)(g * 8) * H3z;
#pragma unroll
    for (int u = 0; u < 8; ++u) {
      w[u][0] = Wr[0]; w[u][1] = Wr[512]; w[u][2] = Wr[1024];
      Wr += H3z;
    }
  };
  auto compg = [&](f32x4 (&w)[8][3], int g) {
#pragma unroll
    for (int u = 0; u < 8; ++u) {
#pragma unroll
      for (int b4 = 0; b4 < 4; ++b4) {
        f32x4 v = vb4[g * 8 + u + b4 * 128];
        pr[b4] = fmaf(v[3], w[u][0][3], fmaf(v[2], w[u][0][2], fmaf(v[1], w[u][0][1], fmaf(v[0], w[u][0][0], pr[b4]))));
        pz[b4] = fmaf(v[3], w[u][1][3], fmaf(v[2], w[u][1][2], fmaf(v[1], w[u][1][1], fmaf(v[0], w[u][1][0], pz[b4]))));
        pn[b4] = fmaf(v[3], w[u][2][3], fmaf(v[2], w[u][2][2], fmaf(v[1], w[u][2][1], fmaf(v[0], w[u][2][0], pn[b4]))));
      }
    }
  };
#pragma unroll
  for (int g = 0; g < G; g += 2) {
    if (g + 1 < G) loadg(wB, g + 1);
    compg(wA, g);
    if (g + 2 < G) loadg(wA, g + 2);
    if (g + 1 < G) compg(wB, g + 1);
  }

#pragma unroll
  for (int b4 = 0; b4 < 4; ++b4) {
    part[((0 * 4 + b4) * 4 + kq) * 64 + l] = pr[b4];
    part[((1 * 4 + b4) * 4 + kq) * 64 + l] = pz[b4];
    part[((2 * 4 + b4) * 4 + kq) * 64 + l] = pn[b4];
  }
  __syncthreads();
  // combine + nonlinearity
  {
    const int b4 = tid >> 6, jc = tid & 63;
    const int b = bg * 4 + b4;
    const int jj = jg * 64 + jc;
    float sr = 0.f, sz = 0.f, snx = 0.f, snh = 0.f;
#pragma unroll
    for (int q = 0; q < 4; ++q) {
      sr += part[((0 * 4 + b4) * 4 + q) * 64 + jc];
      sz += part[((1 * 4 + b4) * 4 + q) * 64 + jc];
      float pnq = part[((2 * 4 + b4) * 4 + q) * 64 + jc];
      if (HASX && q < 2) snx += pnq; else snh += pnq;
    }
    float rv = 1.f / (1.f + __expf(-(gir + sr + bhh[jj])));
    float zv = 1.f / (1.f + __expf(-(giz + sz + bhh[512 + jj])));
    float nv = tanhf(gin + snx + rv * (snh + bhh[1024 + jj]));
    float hv = sh[b4 * 512 + jj];
    float hp = (1.f - zv) * nv + zv * hv;
    st_sc(hout + (long)b * 512 + jj, hp);
    if (fout) st_sc(fout + (long)b * fstride + jj, hp);
    if (bfout) bfout[(long)b * 1024 + jj] = f2bf(hp);
  }
}

// ke + republish: block = (b = blk&31, sq = blk>>5) -> rows b*64+sq*16 .. +16.
// Writer XCD (blk&7 = b&7) == attn reader block b's XCD -> normal-cached
// encN/keN are coherent for the reader and L2-resident across 63 steps.
__device__ void ke_phase(int blk, const float* __restrict__ encOut,
                         const float* __restrict__ attn_wT,
                         float* __restrict__ keN, float* __restrict__ encN,
                         float* smem) {
  int b = blk & 31, sq = blk >> 5;
  long r0 = (long)b * 64 + sq * 16;
  int tid = threadIdx.x;
  {
    const f32x4* ep = (const f32x4*)(encOut + r0 * 512);
    f32x4 v[8];
#pragma unroll
    for (int u = 0; u < 8; ++u) v[u] = ld_sc_nw(ep + tid + u * 256);
    wait_vm0();
    f32x4* en = (f32x4*)(encN + r0 * 512);
#pragma unroll
    for (int u = 0; u < 8; ++u) {
      ((f32x4*)smem)[tid + u * 256] = v[u];
      en[tid + u * 256] = v[u];
    }
  }
  __syncthreads();
  int jj = tid & 63, rq = tid >> 6;
  float acc[4][8];
#pragma unroll
  for (int r = 0; r < 4; ++r)
#pragma unroll
    for (int jc = 0; jc < 8; ++jc) acc[r][jc] = 0.f;
#pragma unroll 2
  for (int k = 0; k < 512; ++k) {
    float w[8];
#pragma unroll
    for (int jc = 0; jc < 8; ++jc) w[jc] = attn_wT[(long)k * 512 + jc * 64 + jj];
#pragma unroll
    for (int r = 0; r < 4; ++r) {
      float e = smem[(rq * 4 + r) * 512 + k];
#pragma unroll
      for (int jc = 0; jc < 8; ++jc) acc[r][jc] = fmaf(e, w[jc], acc[r][jc]);
    }
  }
#pragma unroll
  for (int r = 0; r < 4; ++r)
#pragma unroll
    for (int jc = 0; jc < 8; ++jc)
      keN[(r0 + rq * 4 + r) * 512 + jc * 64 + jj] = acc[r][jc];
}

__device__ void attn_phase(int b, const float* __restrict__ d1,
                           const float* __restrict__ keN,
                           const float* __restrict__ encN,
                           const int* __restrict__ src,
                           float* __restrict__ ctxn,
                           unsigned short* __restrict__ bfctx, float* smem) {
  float* sd = smem;
  float* sc = smem + 512;
  int tid = threadIdx.x;
  {
    float a, c;
    ld2f_sc(d1 + b * 512 + tid, d1 + b * 512 + tid + 256, a, c);
    sd[tid] = a;
    sd[tid + 256] = c;
  }
  __syncthreads();
  int s = tid >> 2, q = tid & 3;
  const float4* kp = (const float4*)(keN + ((long)b * 64 + s) * 512 + q * 128);
  const float4* dp = (const float4*)(sd + q * 128);
  float p = 0.f;
#pragma unroll 8
  for (int i = 0; i < 32; ++i) {
    float4 v = kp[i];
    float4 d = dp[i];
    p += v.x * d.x + v.y * d.y + v.z * d.z + v.w * d.w;
  }
  p += __shfl_xor(p, 1);
  p += __shfl_xor(p, 2);
  if (q == 0) sc[s] = (src[b * 64 + s] == 0) ? -1e9f : p;
  __syncthreads();
  if (tid < 64) {
    float v = sc[tid];
    float m = v;
    for (int o = 32; o; o >>= 1) m = fmaxf(m, __shfl_xor(m, o));
    float e = __expf(v - m);
    float sum = e;
    for (int o = 32; o; o >>= 1) sum += __shfl_xor(sum, o);
    sc[tid] = e / sum;
  }
  __syncthreads();
  float a0 = 0.f, a1 = 0.f;
#pragma unroll 4
  for (int s2 = 0; s2 < 64; ++s2) {
    float w = sc[s2];
    const float* er = encN + ((long)b * 64 + s2) * 512;
    a0 = fmaf(w, er[tid], a0);
    a1 = fmaf(w, er[tid + 256], a1);
  }
  st_sc(ctxn + b * 512 + tid, a0);
  st_sc(ctxn + b * 512 + tid + 256, a1);
  bfctx[b * 1024 + tid] = f2bf(a0);
  bfctx[b * 1024 + tid + 256] = f2bf(a1);
}

__global__ __launch_bounds__(256, 1) void k_persist(PP P) {
  __shared__ float smem[8192];  // 32KB
  int blk = blockIdx.x;
  unsigned ph = 0;
  // ---- encoder: layer1 pipelined one step behind layer0 ----
  for (int i = 0; i < Sz + 1; ++i) {
    if (i < Sz && blk < 64) {
      gru_cell<0>(blk, P.W4e0, P.giEnc + (long)i * 49152, nullptr, P.enc_bhh0,
                  nullptr, P.h0 + (i & 1) * 16384, P.h0 + ((i + 1) & 1) * 16384,
                  nullptr, 0, nullptr, smem);
    } else if (i >= 1 && blk >= 64) {
      int t = i - 1;
      gru_cell<1>(blk - 64, P.W4e1, nullptr, P.enc_bih1, P.enc_bhh1,
                  P.h0 + (i & 1) * 16384, P.h1 + (t & 1) * 16384,
                  P.h1 + ((t + 1) & 1) * 16384,
                  P.encOut + (long)t * 512, (long)Sz * 512, nullptr, smem);
    }
    gsync(P.flags, ++ph);
  }
  // ---- ke + republish encN/keN on reader-aligned XCDs ----
  ke_phase(blk, P.encOut, P.wtAttn, P.keN, P.encN, smem);
  gsync(P.flags, ++ph);
  // ---- decoder ----
  for (int t = 0; t < Tdec; ++t) {
    int cs = t & 1, ns = (t + 1) & 1;
    const float* d0in = (t == 0) ? P.h0 : P.d0 + cs * 16384;  // enc finals slot 0
    const float* d1in = (t == 0) ? P.h1 : P.d1 + cs * 16384;
    if (blk < 64) {
      gru_cell<1>(blk, P.W4d0, P.giDec + (long)t * 49152, nullptr, P.dec_bhh0,
                  P.ctx + cs * 16384, d0in, P.d0 + ns * 16384,
                  nullptr, 0, nullptr, smem);
    }
    gsync(P.flags, ++ph);
    if (blk < 64) {
      gru_cell<1>(blk, P.W4d1, nullptr, P.dec_bih1, P.dec_bhh1,
                  P.d0 + ns * 16384, d1in, P.d1 + ns * 16384,
                  nullptr, 0, P.d1ctxBf + (long)t * 32768, smem);
    }
    gsync(P.flags, ++ph);
    if (blk < 32) {
      attn_phase(blk, P.d1 + ns * 16384, P.keN, P.encN, P.src,
                 P.ctx + ns * 16384, P.d1ctxBf + (long)t * 32768 + 512, smem);
    }
    gsync(P.flags, ++ph);
  }
}

// ---------------- final bf16 MFMA GEMM (validated) ----------------
__global__ __launch_bounds__(256)
void k_out_gemm(const unsigned short* __restrict__ A, const unsigned short* __restrict__ Bw,
                const float* __restrict__ bias, float* __restrict__ out) {
  __shared__ __align__(16) char lds[32768];
  int bid = blockIdx.x;
  int bm = bid & 15, bn = bid >> 4;
  long m0 = (long)bm * 128, n0 = (long)bn * 128;
  int tid = threadIdx.x, lane = tid & 63, wid = tid >> 6;
  int wm = wid >> 1, wn = wid & 1;
  floatx4 acc[4][4];
#pragma unroll
  for (int i = 0; i < 4; i++)
#pragma unroll
    for (int jx = 0; jx < 4; jx++) acc[i][jx] = (floatx4){0.f, 0.f, 0.f, 0.f};

  int rl = lane >> 3;
  int kb = (((lane & 7) ^ rl) << 4);

  for (int kt = 0; kt < 16; ++kt) {
    long kbyte0 = (long)kt * 128;
#pragma unroll
    for (int q = 0; q < 4; ++q) {
      int c = wid * 4 + q;
      int row = c * 8 + rl;
      const char* ga = (const char*)A + (m0 + row) * 2048 + kbyte0 + kb;
      const char* gb = (const char*)Bw + (n0 + row) * 2048 + kbyte0 + kb;
      __builtin_amdgcn_global_load_lds(
          (const __attribute__((address_space(1))) void*)ga,
          (__attribute__((address_space(3))) void*)(lds + (c << 10)), 16, 0, 0);
      __builtin_amdgcn_global_load_lds(
          (const __attribute__((address_space(1))) void*)gb,
          (__attribute__((address_space(3))) void*)(lds + 16384 + (c << 10)), 16, 0, 0);
    }
    asm volatile("s_waitcnt vmcnt(0)" ::: "memory");
    __syncthreads();
#pragma unroll
    for (int kk = 0; kk < 2; ++kk) {
      shortx8 af[4], bf[4];
#pragma unroll
      for (int f = 0; f < 4; ++f) {
        int rowA = wm * 64 + f * 16 + (lane & 15);
        int cbA = (kk * 64 + ((lane >> 4) << 4)) ^ ((rowA & 7) << 4);
        af[f] = *(const shortx8*)(lds + rowA * 128 + cbA);
        int rowB = wn * 64 + f * 16 + (lane & 15);
        int cbB = (kk * 64 + ((lane >> 4) << 4)) ^ ((rowB & 7) << 4);
        bf[f] = *(const shortx8*)(lds + 16384 + rowB * 128 + cbB);
      }
#pragma unroll
      for (int mf = 0; mf < 4; ++mf)
#pragma unroll
        for (int nf = 0; nf < 4; ++nf)
          acc[mf][nf] = __builtin_amdgcn_mfma_f32_16x16x32_bf16(af[mf], bf[nf], acc[mf][nf], 0, 0, 0);
    }
    __syncthreads();
  }
#pragma unroll
  for (int mf = 0; mf < 4; ++mf) {
#pragma unroll
    for (int nf = 0; nf < 4; ++nf) {
      long gn = n0 + wn * 64 + nf * 16 + (lane & 15);
      float bb = bias[gn];
#pragma unroll
      for (int r = 0; r < 4; ++r) {
        long gm = m0 + wm * 64 + mf * 16 + ((lane >> 4) * 4) + r;
        if (gm < (long)Tdec * Bz) {
          long t = gm >> 5, b = gm & 31;
          out[(b * Tdec + t) * (long)Vz + gn] = acc[mf][nf][r] + bb;
        }
      }
    }
  }
}

extern "C" void kernel_launch(void* const* d_in, const int* in_sizes, int n_in,
                              void* d_out, int out_size, void* d_ws, size_t ws_size,
                              hipStream_t stream) {
  const int*   src      = (const int*)d_in[0];
  const int*   tgt      = (const int*)d_in[1];
  const float* enc_emb  = (const float*)d_in[2];
  const float* enc_wih0 = (const float*)d_in[3];
  const float* enc_whh0 = (const float*)d_in[4];
  const float* enc_bih0 = (const float*)d_in[5];
  const float* enc_bhh0 = (const float*)d_in[6];
  const float* enc_wih1 = (const float*)d_in[7];
  const float* enc_whh1 = (const float*)d_in[8];
  const float* enc_bih1 = (const float*)d_in[9];
  const float* enc_bhh1 = (const float*)d_in[10];
  const float* dec_emb  = (const float*)d_in[11];
  const float* dec_wih0 = (const float*)d_in[12];
  const float* dec_whh0 = (const float*)d_in[13];
  const float* dec_bih0 = (const float*)d_in[14];
  const float* dec_bhh0 = (const float*)d_in[15];
  const float* dec_wih1 = (const float*)d_in[16];
  const float* dec_whh1 = (const float*)d_in[17];
  const float* dec_bih1 = (const float*)d_in[18];
  const float* dec_bhh1 = (const float*)d_in[19];
  const float* attn_w   = (const float*)d_in[20];
  const float* out_w    = (const float*)d_in[21];
  const float* out_b    = (const float*)d_in[22];
  float* out = (float*)d_out;

  char* ws = (char*)d_ws;
  size_t off = 0;
  auto alloc = [&](size_t bytes) -> char* {
    char* p = ws + off;
    off += (bytes + 255) & ~(size_t)255;
    return p;
  };
  float* W4embE = (float*)alloc((size_t)Ez * H3z * 4);
  float* W4embD = (float*)alloc((size_t)Ez * H3z * 4);
  float* W4e0   = (float*)alloc((size_t)Hz * H3z * 4);
  float* W4e1   = (float*)alloc((size_t)2 * Hz * H3z * 4);
  float* W4d0   = (float*)alloc((size_t)2 * Hz * H3z * 4);
  float* W4d1   = (float*)alloc((size_t)2 * Hz * H3z * 4);
  float* wtAttn = (float*)alloc((size_t)Hz * Hz * 4);
  float* giEnc  = (float*)alloc((size_t)Sz * Bz * H3z * 4);
  float* giDec  = (float*)alloc((size_t)Tdec * Bz * H3z * 4);
  float* encOut = (float*)alloc((size_t)Bz * Sz * Hz * 4);
  float* encN   = (float*)alloc((size_t)Bz * Sz * Hz * 4);
  float* keN    = (float*)alloc((size_t)Bz * Sz * Hz * 4);
  float* h0buf  = (float*)alloc((size_t)2 * Bz * Hz * 4);
  float* h1buf  = (float*)alloc((size_t)2 * Bz * Hz * 4);
  float* d0buf  = (float*)alloc((size_t)2 * Bz * Hz * 4);
  float* d1buf  = (float*)alloc((size_t)2 * Bz * Hz * 4);
  float* ctxbuf = (float*)alloc((size_t)2 * Bz * Hz * 4);
  unsigned short* d1ctxBf = (unsigned short*)alloc((size_t)2048 * 1024 * 2);
  unsigned short* outwBf  = (unsigned short*)alloc((size_t)Vz * 1024 * 2);
  unsigned* flags = (unsigned*)alloc(NB * 4);
  if (off > ws_size) return;

  dim3 tb(256);
  k_pack4<<<dim3(4, 96), tb, 0, stream>>>(enc_wih0, Ez, 0, W4embE, 0);
  k_pack4<<<dim3(4, 96), tb, 0, stream>>>(dec_wih0, Ez + Hz, 0, W4embD, 0);
  k_pack4<<<dim3(8, 96), tb, 0, stream>>>(enc_whh0, Hz, 0, W4e0, 0);
  k_pack4<<<dim3(8, 96), tb, 0, stream>>>(enc_wih1, Hz, 0, W4e1, 0);
  k_pack4<<<dim3(8, 96), tb, 0, stream>>>(enc_whh1, Hz, 0, W4e1, 128);
  k_pack4<<<dim3(8, 96), tb, 0, stream>>>(dec_wih0, Ez + Hz, Ez, W4d0, 0);
  k_pack4<<<dim3(8, 96), tb, 0, stream>>>(dec_whh0, Hz, 0, W4d0, 128);
  k_pack4<<<dim3(8, 96), tb, 0, stream>>>(dec_wih1, Hz, 0, W4d1, 0);
  k_pack4<<<dim3(8, 96), tb, 0, stream>>>(dec_whh1, Hz, 0, W4d1, 128);
  k_transpose<<<dim3(Hz / 32, Hz / 32), tb, 0, stream>>>(attn_w, Hz, Hz, 0, wtAttn);

  hipMemsetAsync(h0buf, 0, (size_t)2 * Bz * Hz * 4, stream);
  hipMemsetAsync(h1buf, 0, (size_t)2 * Bz * Hz * 4, stream);
  hipMemsetAsync(ctxbuf, 0, (size_t)2 * Bz * Hz * 4, stream);
  hipMemsetAsync(d1ctxBf + (size_t)2016 * 1024, 0, (size_t)32 * 1024 * 2, stream);
  hipMemsetAsync(flags, 0, NB * 4, stream);

  k_embed_gi<<<24 * 128, tb, 0, stream>>>(src, enc_emb, W4embE, enc_bih0, giEnc);
  k_embed_gi<<<24 * 126, tb, 0, stream>>>(tgt, dec_emb, W4embD, dec_bih0, giDec);
  k_f2bf<<<2048, tb, 0, stream>>>(out_w, outwBf, (long)Vz * 1024 / 4);

  PP pp;
  pp.giEnc = giEnc; pp.giDec = giDec;
  pp.W4e0 = W4e0; pp.W4e1 = W4e1; pp.W4d0 = W4d0; pp.W4d1 = W4d1;
  pp.enc_bhh0 = enc_bhh0; pp.enc_bih1 = enc_bih1; pp.enc_bhh1 = enc_bhh1;
  pp.dec_bhh0 = dec_bhh0; pp.dec_bih1 = dec_bih1; pp.dec_bhh1 = dec_bhh1;
  pp.wtAttn = wtAttn; pp.src = src;
  pp.h0 = h0buf; pp.h1 = h1buf; pp.d0 = d0buf; pp.d1 = d1buf; pp.ctx = ctxbuf;
  pp.encOut = encOut; pp.encN = encN; pp.keN = keN;
  pp.d1ctxBf = d1ctxBf; pp.flags = flags;
  k_persist<<<NB, tb, 0, stream>>>(pp);

  k_out_gemm<<<16 * 250, tb, 0, stream>>>(d1ctxBf, outwBf, out_b, out);
}

// Round 6
// 4638.611 us; speedup vs baseline: 2.4180x; 2.4180x over previous
//
#include <hip/hip_runtime.h>

#define Bz   32
#define Sz   64
#define Tdec 63
#define Ez   256
#define Hz   512
#define H3z  1536
#define Vz   32000
#define NB   128   // persistent grid blocks

typedef __attribute__((ext_vector_type(4))) float f32x4;
typedef __attribute__((ext_vector_type(4))) float floatx4;
typedef __attribute__((ext_vector_type(8))) short shortx8;
typedef __attribute__((ext_vector_type(8))) unsigned short u16x8;

__device__ __forceinline__ unsigned short f2bf(float f) {
  unsigned x = __float_as_uint(f);
  unsigned r = (x + 0x7fffu + ((x >> 16) & 1u)) >> 16;
  return (unsigned short)r;
}

// ======== sc0/sc1 (MALL-coherent, L1/L2-bypass) access helpers ========
__device__ __forceinline__ f32x4 ld_sc_nw(const f32x4* p) {  // no wait
  f32x4 r;
  asm volatile("global_load_dwordx4 %0, %1, off sc0 sc1" : "=&v"(r) : "v"(p));
  return r;
}
__device__ __forceinline__ void wait_vm0() {
  asm volatile("s_waitcnt vmcnt(0)" ::: "memory");
}
__device__ __forceinline__ void ld2f_sc(const float* p0, const float* p1,
                                        float& a, float& b) {
  asm volatile(
      "global_load_dword %0, %2, off sc0 sc1\n\t"
      "global_load_dword %1, %3, off sc0 sc1\n\t"
      "s_waitcnt vmcnt(0)"
      : "=&v"(a), "=&v"(b) : "v"(p0), "v"(p1) : "memory");
}
__device__ __forceinline__ void st_sc(float* p, float v) {
  asm volatile("global_store_dword %0, %1, off sc0 sc1" :: "v"(p), "v"(v) : "memory");
}
__device__ __forceinline__ void st_flag(unsigned* p, unsigned v) {
  asm volatile("global_store_dword %0, %1, off sc0 sc1" :: "v"(p), "v"(v) : "memory");
}
__device__ __forceinline__ void ld2u_sc(const unsigned* p0, const unsigned* p1,
                                        unsigned& a, unsigned& b) {
  asm volatile(
      "global_load_dword %0, %2, off sc0 sc1\n\t"
      "global_load_dword %1, %3, off sc0 sc1\n\t"
      "s_waitcnt vmcnt(0)"
      : "=&v"(a), "=&v"(b) : "v"(p0), "v"(p1) : "memory");
}

// ---------------- generic transpose: out[c][r] = in[r][c0+c] ----------------
__global__ __launch_bounds__(256)
void k_transpose(const float* __restrict__ in, int R, int Ctot, int c0,
                 float* __restrict__ out) {
  __shared__ float tile[32][33];
  int ct = blockIdx.x * 32;
  int rt = blockIdx.y * 32;
  int lx = threadIdx.x & 31, ly = threadIdx.x >> 5;
#pragma unroll
  for (int i = 0; i < 32; i += 8)
    tile[ly + i][lx] = in[(long)(rt + ly + i) * Ctot + c0 + ct + lx];
  __syncthreads();
#pragma unroll
  for (int i = 0; i < 32; i += 8)
    out[(long)(ct + ly + i) * R + rt + lx] = tile[lx][ly + i];
}

// ---- pack fp32 weights (embed GEMM): out[(k4)*1536*4 + j*4 + q] ----
__global__ __launch_bounds__(256)
void k_pack4(const float* __restrict__ in, int rs, int c0,
             float* __restrict__ out, int k4off) {
  int jl = threadIdx.x & 15, k4l = threadIdx.x >> 4;
  int j = blockIdx.y * 16 + jl;
  int k4 = blockIdx.x * 16 + k4l;
  float4 v = *(const float4*)(in + (long)j * rs + c0 + k4 * 4);
  *(float4*)(out + ((long)(k4 + k4off) * H3z + j) * 4) = v;
}

// ---- pack recurrent weights to bf16: out[(k8+k8off)*1536 + j][8] ----
__global__ __launch_bounds__(256)
void k_packbf(const float* __restrict__ in, int rs, int c0,
              unsigned short* __restrict__ out, int k8off) {
  int jl = threadIdx.x & 31, k8l = threadIdx.x >> 5;  // 32 j x 8 k8
  int j = blockIdx.y * 32 + jl;
  int k8 = blockIdx.x * 8 + k8l;
  const float* src = in + (long)j * rs + c0 + k8 * 8;
  float4 a = *(const float4*)src;
  float4 b = *(const float4*)(src + 4);
  u16x8 o;
  o[0] = f2bf(a.x); o[1] = f2bf(a.y); o[2] = f2bf(a.z); o[3] = f2bf(a.w);
  o[4] = f2bf(b.x); o[5] = f2bf(b.y); o[6] = f2bf(b.z); o[7] = f2bf(b.w);
  *(u16x8*)(out + ((long)(k8 + k8off) * H3z + j) * 8) = o;
}

// -------- embed + input-GEMM with packed fp32 weights W4[k4][1536][4], K=256
__global__ __launch_bounds__(256)
void k_embed_gi(const int* __restrict__ toks, const float* __restrict__ emb,
                const float* __restrict__ W4, const float* __restrict__ bias,
                float* __restrict__ G) {
  __shared__ float se[16][Ez];
  int jg = blockIdx.x % 24;
  int rg = blockIdx.x / 24;
  int r0 = rg * 16;
  int tid = threadIdx.x;
  for (int c = tid; c < 16 * Ez; c += 256) {
    int rl = c >> 8;
    int k = c & 255;
    int r = r0 + rl;
    int tok = toks[(r & 31) * 64 + (r >> 5)];
    se[rl][k] = emb[(long)tok * Ez + k];
  }
  __syncthreads();
  int jj = tid & 63, rq = tid >> 6;
  int j = jg * 64 + jj;
  float a0 = 0.f, a1 = 0.f, a2 = 0.f, a3 = 0.f;
#pragma unroll 4
  for (int k4 = 0; k4 < 64; ++k4) {
    float4 w = *(const float4*)(W4 + ((long)k4 * H3z + j) * 4);
    const float* s0 = &se[rq * 4 + 0][k4 * 4];
    const float* s1 = &se[rq * 4 + 1][k4 * 4];
    const float* s2 = &se[rq * 4 + 2][k4 * 4];
    const float* s3 = &se[rq * 4 + 3][k4 * 4];
    a0 = fmaf(s0[3], w.w, fmaf(s0[2], w.z, fmaf(s0[1], w.y, fmaf(s0[0], w.x, a0))));
    a1 = fmaf(s1[3], w.w, fmaf(s1[2], w.z, fmaf(s1[1], w.y, fmaf(s1[0], w.x, a1))));
    a2 = fmaf(s2[3], w.w, fmaf(s2[2], w.z, fmaf(s2[1], w.y, fmaf(s2[0], w.x, a2))));
    a3 = fmaf(s3[3], w.w, fmaf(s3[2], w.z, fmaf(s3[1], w.y, fmaf(s3[0], w.x, a3))));
  }
  float bj = bias[j];
  G[(long)(r0 + rq * 4 + 0) * H3z + j] = a0 + bj;
  G[(long)(r0 + rq * 4 + 1) * H3z + j] = a1 + bj;
  G[(long)(r0 + rq * 4 + 2) * H3z + j] = a2 + bj;
  G[(long)(r0 + rq * 4 + 3) * H3z + j] = a3 + bj;
}

// ---------------- fp32 -> bf16 convert ----------------
__global__ void k_f2bf(const float* __restrict__ in, unsigned short* __restrict__ out, long n4) {
  long i = (long)blockIdx.x * blockDim.x + threadIdx.x;
  long stride = (long)gridDim.x * blockDim.x;
  for (; i < n4; i += stride) {
    float4 v = ((const float4*)in)[i];
    ushort4 o;
    o.x = f2bf(v.x); o.y = f2bf(v.y); o.z = f2bf(v.z); o.w = f2bf(v.w);
    ((ushort4*)out)[i] = o;
  }
}

// ================= persistent recurrence kernel =================
struct PP {
  const float* giEnc;
  const float* giDec;
  const unsigned short* W8e0;   // [64 k8][1536][8]   enc whh0
  const unsigned short* W8e1;   // [128 k8][1536][8]  enc wih1 | whh1
  const unsigned short* W8d0;   // [128 k8][1536][8]  dec wih0-ctx | whh0
  const unsigned short* W8d1;   // [128 k8][1536][8]  dec wih1 | whh1
  const float* enc_bhh0;
  const float* enc_bih1;
  const float* enc_bhh1;
  const float* dec_bhh0;
  const float* dec_bih1;
  const float* dec_bhh1;
  const float* wtAttn;
  const int* src;
  float* h0; float* h1; float* d0; float* d1; float* ctx;
  float* encOut;   // sc-space [32][64][512]
  float* encN;     // normal-cached copy, XCD-local to attn readers
  float* keN;      // normal-cached, XCD-local to attn readers
  unsigned* flags; // [NB], monotone phase counters
  unsigned short* d1ctxBf;
};

// Grid barrier: drain sc stores (vmcnt), publish flag (sc), spin on sc flags.
__device__ __forceinline__ void gsync(unsigned* flags, unsigned ph) {
  wait_vm0();
  __syncthreads();
  int tid = threadIdx.x;
  if (tid == 0) st_flag(&flags[blockIdx.x], ph);
  if (tid < 64) {
    const unsigned* p0 = &flags[tid];
    const unsigned* p1 = &flags[tid + 64];
    for (;;) {
      unsigned f0, f1;
      ld2u_sc(p0, p1, f0, f1);
      if (!__any(f0 < ph || f1 < ph)) break;
      __builtin_amdgcn_s_sleep(1);
    }
  }
  __syncthreads();
}

// GRU cell over 64 blocks: jg=blkid&7 (== XCD -> bf16 weights L2-resident),
// bg=blkid>>3 (4 batch rows). Wave kq owns K-quarter kq.
// bf16 weights [k8][1536][8]; moderate pipeline: 2-row groups, double-buffered
// (12 loads in flight — below the L2-allocation cliff seen in R5).
template <int HASX>
__device__ __forceinline__ void gru_cell(
    int blkid, const unsigned short* __restrict__ W8,
    const float* __restrict__ gi, const float* __restrict__ bih,
    const float* __restrict__ bhh,
    const float* __restrict__ xin, const float* __restrict__ hin,
    float* __restrict__ hout, float* __restrict__ fout, long fstride,
    unsigned short* __restrict__ bfout, float* smem) {
  float* sh = smem;            // [4][512]
  float* sx = smem + 2048;     // [4][512]
  float* part = smem + 4096;   // [3][4][4][64]
  const int jg = blkid & 7, bg = blkid >> 3;
  const int tid = threadIdx.x;
  const int l = tid & 63;
  const int kq = tid >> 6;
  const int j = jg * 64 + l;
  constexpr int Q8 = HASX ? 32 : 16;   // k8 rows per wave-quarter
  constexpr int G8 = Q8 / 2;           // 2-row groups
  const u16x8* Wr0 = (const u16x8*)W8 + (long)(kq * Q8) * H3z + j;

  u16x8 wA[2][3], wB[2][3];
  // group-0 weight prefetch (independent of h)
  {
    const u16x8* Wr = Wr0;
    wA[0][0] = Wr[0];    wA[0][1] = Wr[512];  wA[0][2] = Wr[1024];
    wA[1][0] = Wr[1536]; wA[1][1] = Wr[2048]; wA[1][2] = Wr[2560];
  }
  // gi/bih prefetch for the combine stage (mapping: b4=tid>>6, jc=tid&63)
  float gir = 0.f, giz = 0.f, gin = 0.f;
  {
    const int b4 = tid >> 6, jc = tid & 63;
    const int b = bg * 4 + b4, jj = jg * 64 + jc;
    if (gi) {
      gir = gi[(long)b * H3z + jj];
      giz = gi[(long)b * H3z + 512 + jj];
      gin = gi[(long)b * H3z + 1024 + jj];
    }
    if (bih) { gir += bih[jj]; giz += bih[512 + jj]; gin += bih[1024 + jj]; }
  }
  // stage h (and x) via sc loads
  {
    const f32x4* hp = (const f32x4*)(hin + bg * 2048);
    if (HASX) {
      const f32x4* xp = (const f32x4*)(xin + bg * 2048);
      f32x4 a = ld_sc_nw(hp + tid);
      f32x4 b = ld_sc_nw(hp + tid + 256);
      f32x4 c = ld_sc_nw(xp + tid);
      f32x4 d = ld_sc_nw(xp + tid + 256);
      wait_vm0();
      ((f32x4*)sh)[tid] = a; ((f32x4*)sh)[tid + 256] = b;
      ((f32x4*)sx)[tid] = c; ((f32x4*)sx)[tid + 256] = d;
    } else {
      f32x4 a = ld_sc_nw(hp + tid);
      f32x4 b = ld_sc_nw(hp + tid + 256);
      wait_vm0();
      ((f32x4*)sh)[tid] = a; ((f32x4*)sh)[tid + 256] = b;
    }
  }
  __syncthreads();

  const float* vb;
  if (HASX) vb = (kq < 2) ? (sx + kq * 256) : (sh + (kq - 2) * 256);
  else      vb = sh + kq * 128;
  float pr[4] = {0, 0, 0, 0}, pz[4] = {0, 0, 0, 0}, pn[4] = {0, 0, 0, 0};

  auto loadg = [&](u16x8 (&w)[2][3], int g) {
    const u16x8* Wr = Wr0 + (long)(2 * g) * H3z;
    w[0][0] = Wr[0];    w[0][1] = Wr[512];  w[0][2] = Wr[1024];
    w[1][0] = Wr[1536]; w[1][1] = Wr[2048]; w[1][2] = Wr[2560];
  };
  auto compg = [&](u16x8 (&w)[2][3], int g) {
#pragma unroll
    for (int r = 0; r < 2; ++r) {
      const int kk = 2 * g + r;
      float f0[8], f1[8], f2[8];
#pragma unroll
      for (int e = 0; e < 8; ++e) {
        f0[e] = __uint_as_float((unsigned)w[r][0][e] << 16);
        f1[e] = __uint_as_float((unsigned)w[r][1][e] << 16);
        f2[e] = __uint_as_float((unsigned)w[r][2][e] << 16);
      }
#pragma unroll
      for (int b4 = 0; b4 < 4; ++b4) {
        const float* v = vb + kk * 8 + b4 * 512;   // wave-uniform: LDS broadcast
        f32x4 v0 = *(const f32x4*)v;
        f32x4 v1 = *(const f32x4*)(v + 4);
#pragma unroll
        for (int e = 0; e < 4; ++e) {
          pr[b4] = fmaf(v0[e], f0[e], pr[b4]);
          pz[b4] = fmaf(v0[e], f1[e], pz[b4]);
          pn[b4] = fmaf(v0[e], f2[e], pn[b4]);
        }
#pragma unroll
        for (int e = 0; e < 4; ++e) {
          pr[b4] = fmaf(v1[e], f0[4 + e], pr[b4]);
          pz[b4] = fmaf(v1[e], f1[4 + e], pz[b4]);
          pn[b4] = fmaf(v1[e], f2[4 + e], pn[b4]);
        }
      }
    }
  };
#pragma unroll
  for (int g = 0; g < G8; g += 2) {
    if (g + 1 < G8) loadg(wB, g + 1);
    compg(wA, g);
    if (g + 2 < G8) loadg(wA, g + 2);
    if (g + 1 < G8) compg(wB, g + 1);
  }

#pragma unroll
  for (int b4 = 0; b4 < 4; ++b4) {
    part[((0 * 4 + b4) * 4 + kq) * 64 + l] = pr[b4];
    part[((1 * 4 + b4) * 4 + kq) * 64 + l] = pz[b4];
    part[((2 * 4 + b4) * 4 + kq) * 64 + l] = pn[b4];
  }
  __syncthreads();
  // combine + nonlinearity
  {
    const int b4 = tid >> 6, jc = tid & 63;
    const int b = bg * 4 + b4;
    const int jj = jg * 64 + jc;
    float sr = 0.f, sz = 0.f, snx = 0.f, snh = 0.f;
#pragma unroll
    for (int q = 0; q < 4; ++q) {
      sr += part[((0 * 4 + b4) * 4 + q) * 64 + jc];
      sz += part[((1 * 4 + b4) * 4 + q) * 64 + jc];
      float pnq = part[((2 * 4 + b4) * 4 + q) * 64 + jc];
      if (HASX && q < 2) snx += pnq; else snh += pnq;
    }
    float rv = 1.f / (1.f + __expf(-(gir + sr + bhh[jj])));
    float zv = 1.f / (1.f + __expf(-(giz + sz + bhh[512 + jj])));
    float nv = tanhf(gin + snx + rv * (snh + bhh[1024 + jj]));
    float hv = sh[b4 * 512 + jj];
    float hp = (1.f - zv) * nv + zv * hv;
    st_sc(hout + (long)b * 512 + jj, hp);
    if (fout) st_sc(fout + (long)b * fstride + jj, hp);
    if (bfout) bfout[(long)b * 1024 + jj] = f2bf(hp);
  }
}

// ke + republish: block = (b = blk&31, sq = blk>>5) -> rows b*64+sq*16 .. +16.
// Writer XCD (blk%8 = b%8) == attn reader block b's XCD.
__device__ void ke_phase(int blk, const float* __restrict__ encOut,
                         const float* __restrict__ attn_wT,
                         float* __restrict__ keN, float* __restrict__ encN,
                         float* smem) {
  int b = blk & 31, sq = blk >> 5;
  long r0 = (long)b * 64 + sq * 16;
  int tid = threadIdx.x;
  {
    const f32x4* ep = (const f32x4*)(encOut + r0 * 512);
    f32x4 v[8];
#pragma unroll
    for (int u = 0; u < 8; ++u) v[u] = ld_sc_nw(ep + tid + u * 256);
    wait_vm0();
    f32x4* en = (f32x4*)(encN + r0 * 512);
#pragma unroll
    for (int u = 0; u < 8; ++u) {
      ((f32x4*)smem)[tid + u * 256] = v[u];
      en[tid + u * 256] = v[u];
    }
  }
  __syncthreads();
  int jj = tid & 63, rq = tid >> 6;
  float acc[4][8];
#pragma unroll
  for (int r = 0; r < 4; ++r)
#pragma unroll
    for (int jc = 0; jc < 8; ++jc) acc[r][jc] = 0.f;
#pragma unroll 2
  for (int k = 0; k < 512; ++k) {
    float w[8];
#pragma unroll
    for (int jc = 0; jc < 8; ++jc) w[jc] = attn_wT[(long)k * 512 + jc * 64 + jj];
#pragma unroll
    for (int r = 0; r < 4; ++r) {
      float e = smem[(rq * 4 + r) * 512 + k];
#pragma unroll
      for (int jc = 0; jc < 8; ++jc) acc[r][jc] = fmaf(e, w[jc], acc[r][jc]);
    }
  }
#pragma unroll
  for (int r = 0; r < 4; ++r)
#pragma unroll
    for (int jc = 0; jc < 8; ++jc)
      keN[(r0 + rq * 4 + r) * 512 + jc * 64 + jj] = acc[r][jc];
}

__device__ void attn_phase(int b, const float* __restrict__ d1,
                           const float* __restrict__ keN,
                           const float* __restrict__ encN,
                           const int* __restrict__ src,
                           float* __restrict__ ctxn,
                           unsigned short* __restrict__ bfctx, float* smem) {
  float* sd = smem;
  float* sc = smem + 512;
  int tid = threadIdx.x;
  {
    float a, c;
    ld2f_sc(d1 + b * 512 + tid, d1 + b * 512 + tid + 256, a, c);
    sd[tid] = a;
    sd[tid + 256] = c;
  }
  __syncthreads();
  int s = tid >> 2, q = tid & 3;
  const float4* kp = (const float4*)(keN + ((long)b * 64 + s) * 512 + q * 128);
  const float4* dp = (const float4*)(sd + q * 128);
  float p = 0.f;
#pragma unroll 8
  for (int i = 0; i < 32; ++i) {
    float4 v = kp[i];
    float4 d = dp[i];
    p += v.x * d.x + v.y * d.y + v.z * d.z + v.w * d.w;
  }
  p += __shfl_xor(p, 1);
  p += __shfl_xor(p, 2);
  if (q == 0) sc[s] = (src[b * 64 + s] == 0) ? -1e9f : p;
  __syncthreads();
  if (tid < 64) {
    float v = sc[tid];
    float m = v;
    for (int o = 32; o; o >>= 1) m = fmaxf(m, __shfl_xor(m, o));
    float e = __expf(v - m);
    float sum = e;
    for (int o = 32; o; o >>= 1) sum += __shfl_xor(sum, o);
    sc[tid] = e / sum;
  }
  __syncthreads();
  float a0 = 0.f, a1 = 0.f;
#pragma unroll 4
  for (int s2 = 0; s2 < 64; ++s2) {
    float w = sc[s2];
    const float* er = encN + ((long)b * 64 + s2) * 512;
    a0 = fmaf(w, er[tid], a0);
    a1 = fmaf(w, er[tid + 256], a1);
  }
  st_sc(ctxn + b * 512 + tid, a0);
  st_sc(ctxn + b * 512 + tid + 256, a1);
  bfctx[b * 1024 + tid] = f2bf(a0);
  bfctx[b * 1024 + tid + 256] = f2bf(a1);
}

__global__ __launch_bounds__(256) void k_persist(PP P) {
  __shared__ float smem[8192];  // 32KB
  int blk = blockIdx.x;
  unsigned ph = 0;
  // ---- encoder: layer1 pipelined one step behind layer0 ----
  for (int i = 0; i < Sz + 1; ++i) {
    if (i < Sz && blk < 64) {
      gru_cell<0>(blk, P.W8e0, P.giEnc + (long)i * 49152, nullptr, P.enc_bhh0,
                  nullptr, P.h0 + (i & 1) * 16384, P.h0 + ((i + 1) & 1) * 16384,
                  nullptr, 0, nullptr, smem);
    } else if (i >= 1 && blk >= 64) {
      int t = i - 1;
      gru_cell<1>(blk - 64, P.W8e1, nullptr, P.enc_bih1, P.enc_bhh1,
                  P.h0 + (i & 1) * 16384, P.h1 + (t & 1) * 16384,
                  P.h1 + ((t + 1) & 1) * 16384,
                  P.encOut + (long)t * 512, (long)Sz * 512, nullptr, smem);
    }
    gsync(P.flags, ++ph);
  }
  // ---- ke + republish encN/keN on reader-aligned XCDs ----
  ke_phase(blk, P.encOut, P.wtAttn, P.keN, P.encN, smem);
  gsync(P.flags, ++ph);
  // ---- decoder ----
  for (int t = 0; t < Tdec; ++t) {
    int cs = t & 1, ns = (t + 1) & 1;
    const float* d0in = (t == 0) ? P.h0 : P.d0 + cs * 16384;  // enc finals slot 0
    const float* d1in = (t == 0) ? P.h1 : P.d1 + cs * 16384;
    if (blk < 64) {
      gru_cell<1>(blk, P.W8d0, P.giDec + (long)t * 49152, nullptr, P.dec_bhh0,
                  P.ctx + cs * 16384, d0in, P.d0 + ns * 16384,
                  nullptr, 0, nullptr, smem);
    }
    gsync(P.flags, ++ph);
    if (blk < 64) {
      gru_cell<1>(blk, P.W8d1, nullptr, P.dec_bih1, P.dec_bhh1,
                  P.d0 + ns * 16384, d1in, P.d1 + ns * 16384,
                  nullptr, 0, P.d1ctxBf + (long)t * 32768, smem);
    }
    gsync(P.flags, ++ph);
    if (blk < 32) {
      attn_phase(blk, P.d1 + ns * 16384, P.keN, P.encN, P.src,
                 P.ctx + ns * 16384, P.d1ctxBf + (long)t * 32768 + 512, smem);
    }
    gsync(P.flags, ++ph);
  }
}

// ---------------- final bf16 MFMA GEMM (validated) ----------------
__global__ __launch_bounds__(256)
void k_out_gemm(const unsigned short* __restrict__ A, const unsigned short* __restrict__ Bw,
                const float* __restrict__ bias, float* __restrict__ out) {
  __shared__ __align__(16) char lds[32768];
  int bid = blockIdx.x;
  int bm = bid & 15, bn = bid >> 4;
  long m0 = (long)bm * 128, n0 = (long)bn * 128;
  int tid = threadIdx.x, lane = tid & 63, wid = tid >> 6;
  int wm = wid >> 1, wn = wid & 1;
  floatx4 acc[4][4];
#pragma unroll
  for (int i = 0; i < 4; i++)
#pragma unroll
    for (int jx = 0; jx < 4; jx++) acc[i][jx] = (floatx4){0.f, 0.f, 0.f, 0.f};

  int rl = lane >> 3;
  int kb = (((lane & 7) ^ rl) << 4);

  for (int kt = 0; kt < 16; ++kt) {
    long kbyte0 = (long)kt * 128;
#pragma unroll
    for (int q = 0; q < 4; ++q) {
      int c = wid * 4 + q;
      int row = c * 8 + rl;
      const char* ga = (const char*)A + (m0 + row) * 2048 + kbyte0 + kb;
      const char* gb = (const char*)Bw + (n0 + row) * 2048 + kbyte0 + kb;
      __builtin_amdgcn_global_load_lds(
          (const __attribute__((address_space(1))) void*)ga,
          (__attribute__((address_space(3))) void*)(lds + (c << 10)), 16, 0, 0);
      __builtin_amdgcn_global_load_lds(
          (const __attribute__((address_space(1))) void*)gb,
          (__attribute__((address_space(3))) void*)(lds + 16384 + (c << 10)), 16, 0, 0);
    }
    asm volatile("s_waitcnt vmcnt(0)" ::: "memory");
    __syncthreads();
#pragma unroll
    for (int kk = 0; kk < 2; ++kk) {
      shortx8 af[4], bf[4];
#pragma unroll
      for (int f = 0; f < 4; ++f) {
        int rowA = wm * 64 + f * 16 + (lane & 15);
        int cbA = (kk * 64 + ((lane >> 4) << 4)) ^ ((rowA & 7) << 4);
        af[f] = *(const shortx8*)(lds + rowA * 128 + cbA);
        int rowB = wn * 64 + f * 16 + (lane & 15);
        int cbB = (kk * 64 + ((lane >> 4) << 4)) ^ ((rowB & 7) << 4);
        bf[f] = *(const shortx8*)(lds + 16384 + rowB * 128 + cbB);
      }
#pragma unroll
      for (int mf = 0; mf < 4; ++mf)
#pragma unroll
        for (int nf = 0; nf < 4; ++nf)
          acc[mf][nf] = __builtin_amdgcn_mfma_f32_16x16x32_bf16(af[mf], bf[nf], acc[mf][nf], 0, 0, 0);
    }
    __syncthreads();
  }
#pragma unroll
  for (int mf = 0; mf < 4; ++mf) {
#pragma unroll
    for (int nf = 0; nf < 4; ++nf) {
      long gn = n0 + wn * 64 + nf * 16 + (lane & 15);
      float bb = bias[gn];
#pragma unroll
      for (int r = 0; r < 4; ++r) {
        long gm = m0 + wm * 64 + mf * 16 + ((lane >> 4) * 4) + r;
        if (gm < (long)Tdec * Bz) {
          long t = gm >> 5, b = gm & 31;
          out[(b * Tdec + t) * (long)Vz + gn] = acc[mf][nf][r] + bb;
        }
      }
    }
  }
}

extern "C" void kernel_launch(void* const* d_in, const int* in_sizes, int n_in,
                              void* d_out, int out_size, void* d_ws, size_t ws_size,
                              hipStream_t stream) {
  const int*   src      = (const int*)d_in[0];
  const int*   tgt      = (const int*)d_in[1];
  const float* enc_emb  = (const float*)d_in[2];
  const float* enc_wih0 = (const float*)d_in[3];
  const float* enc_whh0 = (const float*)d_in[4];
  const float* enc_bih0 = (const float*)d_in[5];
  const float* enc_bhh0 = (const float*)d_in[6];
  const float* enc_wih1 = (const float*)d_in[7];
  const float* enc_whh1 = (const float*)d_in[8];
  const float* enc_bih1 = (const float*)d_in[9];
  const float* enc_bhh1 = (const float*)d_in[10];
  const float* dec_emb  = (const float*)d_in[11];
  const float* dec_wih0 = (const float*)d_in[12];
  const float* dec_whh0 = (const float*)d_in[13];
  const float* dec_bih0 = (const float*)d_in[14];
  const float* dec_bhh0 = (const float*)d_in[15];
  const float* dec_wih1 = (const float*)d_in[16];
  const float* dec_whh1 = (const float*)d_in[17];
  const float* dec_bih1 = (const float*)d_in[18];
  const float* dec_bhh1 = (const float*)d_in[19];
  const float* attn_w   = (const float*)d_in[20];
  const float* out_w    = (const float*)d_in[21];
  const float* out_b    = (const float*)d_in[22];
  float* out = (float*)d_out;

  char* ws = (char*)d_ws;
  size_t off = 0;
  auto alloc = [&](size_t bytes) -> char* {
    char* p = ws + off;
    off += (bytes + 255) & ~(size_t)255;
    return p;
  };
  float* W4embE = (float*)alloc((size_t)Ez * H3z * 4);
  float* W4embD = (float*)alloc((size_t)Ez * H3z * 4);
  unsigned short* W8e0 = (unsigned short*)alloc((size_t)64 * H3z * 8 * 2);
  unsigned short* W8e1 = (unsigned short*)alloc((size_t)128 * H3z * 8 * 2);
  unsigned short* W8d0 = (unsigned short*)alloc((size_t)128 * H3z * 8 * 2);
  unsigned short* W8d1 = (unsigned short*)alloc((size_t)128 * H3z * 8 * 2);
  float* wtAttn = (float*)alloc((size_t)Hz * Hz * 4);
  float* giEnc  = (float*)alloc((size_t)Sz * Bz * H3z * 4);
  float* giDec  = (float*)alloc((size_t)Tdec * Bz * H3z * 4);
  float* encOut = (float*)alloc((size_t)Bz * Sz * Hz * 4);
  float* encN   = (float*)alloc((size_t)Bz * Sz * Hz * 4);
  float* keN    = (float*)alloc((size_t)Bz * Sz * Hz * 4);
  float* h0buf  = (float*)alloc((size_t)2 * Bz * Hz * 4);
  float* h1buf  = (float*)alloc((size_t)2 * Bz * Hz * 4);
  float* d0buf  = (float*)alloc((size_t)2 * Bz * Hz * 4);
  float* d1buf  = (float*)alloc((size_t)2 * Bz * Hz * 4);
  float* ctxbuf = (float*)alloc((size_t)2 * Bz * Hz * 4);
  unsigned short* d1ctxBf = (unsigned short*)alloc((size_t)2048 * 1024 * 2);
  unsigned short* outwBf  = (unsigned short*)alloc((size_t)Vz * 1024 * 2);
  unsigned* flags = (unsigned*)alloc(NB * 4);
  if (off > ws_size) return;

  dim3 tb(256);
  k_pack4<<<dim3(4, 96), tb, 0, stream>>>(enc_wih0, Ez, 0, W4embE, 0);
  k_pack4<<<dim3(4, 96), tb, 0, stream>>>(dec_wih0, Ez + Hz, 0, W4embD, 0);
  k_packbf<<<dim3(8, 48), tb, 0, stream>>>(enc_whh0, Hz, 0, W8e0, 0);
  k_packbf<<<dim3(8, 48), tb, 0, stream>>>(enc_wih1, Hz, 0, W8e1, 0);
  k_packbf<<<dim3(8, 48), tb, 0, stream>>>(enc_whh1, Hz, 0, W8e1, 64);
  k_packbf<<<dim3(8, 48), tb, 0, stream>>>(dec_wih0, Ez + Hz, Ez, W8d0, 0);
  k_packbf<<<dim3(8, 48), tb, 0, stream>>>(dec_whh0, Hz, 0, W8d0, 64);
  k_packbf<<<dim3(8, 48), tb, 0, stream>>>(dec_wih1, Hz, 0, W8d1, 0);
  k_packbf<<<dim3(8, 48), tb, 0, stream>>>(dec_whh1, Hz, 0, W8d1, 64);
  k_transpose<<<dim3(Hz / 32, Hz / 32), tb, 0, stream>>>(attn_w, Hz, Hz, 0, wtAttn);

  hipMemsetAsync(h0buf, 0, (size_t)2 * Bz * Hz * 4, stream);
  hipMemsetAsync(h1buf, 0, (size_t)2 * Bz * Hz * 4, stream);
  hipMemsetAsync(ctxbuf, 0, (size_t)2 * Bz * Hz * 4, stream);
  hipMemsetAsync(d1ctxBf + (size_t)2016 * 1024, 0, (size_t)32 * 1024 * 2, stream);
  hipMemsetAsync(flags, 0, NB * 4, stream);

  k_embed_gi<<<24 * 128, tb, 0, stream>>>(src, enc_emb, W4embE, enc_bih0, giEnc);
  k_embed_gi<<<24 * 126, tb, 0, stream>>>(tgt, dec_emb, W4embD, dec_bih0, giDec);
  k_f2bf<<<2048, tb, 0, stream>>>(out_w, outwBf, (long)Vz * 1024 / 4);

  PP pp;
  pp.giEnc = giEnc; pp.giDec = giDec;
  pp.W8e0 = W8e0; pp.W8e1 = W8e1; pp.W8d0 = W8d0; pp.W8d1 = W8d1;
  pp.enc_bhh0 = enc_bhh0; pp.enc_bih1 = enc_bih1; pp.enc_bhh1 = enc_bhh1;
  pp.dec_bhh0 = dec_bhh0; pp.dec_bih1 = dec_bih1; pp.dec_bhh1 = dec_bhh1;
  pp.wtAttn = wtAttn; pp.src = src;
  pp.h0 = h0buf; pp.h1 = h1buf; pp.d0 = d0buf; pp.d1 = d1buf; pp.ctx = ctxbuf;
  pp.encOut = encOut; pp.encN = encN; pp.keN = keN;
  pp.d1ctxBf = d1ctxBf; pp.flags = flags;
  k_persist<<<NB, tb, 0, stream>>>(pp);

  k_out_gemm<<<16 * 250, tb, 0, stream>>>(d1ctxBf, outwBf, out_b, out);
}

// Round 7
// 4377.879 us; speedup vs baseline: 2.5620x; 1.0596x over previous
//
#include <hip/hip_runtime.h>

#define Bz   32
#define Sz   64
#define Tdec 63
#define Ez   256
#define Hz   512
#define H3z  1536
#define Vz   32000
#define NB   128   // persistent grid blocks

typedef __attribute__((ext_vector_type(4))) float f32x4;
typedef __attribute__((ext_vector_type(4))) float floatx4;
typedef __attribute__((ext_vector_type(8))) short shortx8;
typedef __attribute__((ext_vector_type(8))) unsigned short u16x8;

__device__ __forceinline__ unsigned short f2bf(float f) {
  unsigned x = __float_as_uint(f);
  unsigned r = (x + 0x7fffu + ((x >> 16) & 1u)) >> 16;
  return (unsigned short)r;
}
__device__ __forceinline__ float bf2f(unsigned short u) {
  return __uint_as_float((unsigned)u << 16);
}

// ======== sc0/sc1 (MALL-coherent, L1/L2-bypass) access helpers ========
__device__ __forceinline__ f32x4 ld_sc_nw(const f32x4* p) {  // no wait
  f32x4 r;
  asm volatile("global_load_dwordx4 %0, %1, off sc0 sc1" : "=&v"(r) : "v"(p));
  return r;
}
__device__ __forceinline__ void wait_vm0() {
  asm volatile("s_waitcnt vmcnt(0)" ::: "memory");
}
__device__ __forceinline__ void ld1f_sc(const float* p, float& a) {
  asm volatile(
      "global_load_dword %0, %1, off sc0 sc1\n\t"
      "s_waitcnt vmcnt(0)"
      : "=&v"(a) : "v"(p) : "memory");
}
__device__ __forceinline__ void ld4f_sc(const float* p0, const float* p1,
                                        const float* p2, const float* p3,
                                        float& a, float& b, float& c, float& d) {
  asm volatile(
      "global_load_dword %0, %4, off sc0 sc1\n\t"
      "global_load_dword %1, %5, off sc0 sc1\n\t"
      "global_load_dword %2, %6, off sc0 sc1\n\t"
      "global_load_dword %3, %7, off sc0 sc1\n\t"
      "s_waitcnt vmcnt(0)"
      : "=&v"(a), "=&v"(b), "=&v"(c), "=&v"(d)
      : "v"(p0), "v"(p1), "v"(p2), "v"(p3) : "memory");
}
__device__ __forceinline__ void st_sc(float* p, float v) {
  asm volatile("global_store_dword %0, %1, off sc0 sc1" :: "v"(p), "v"(v) : "memory");
}
__device__ __forceinline__ void st_flag(unsigned* p, unsigned v) {
  asm volatile("global_store_dword %0, %1, off sc0 sc1" :: "v"(p), "v"(v) : "memory");
}
__device__ __forceinline__ void ld2u_sc(const unsigned* p0, const unsigned* p1,
                                        unsigned& a, unsigned& b) {
  asm volatile(
      "global_load_dword %0, %2, off sc0 sc1\n\t"
      "global_load_dword %1, %3, off sc0 sc1\n\t"
      "s_waitcnt vmcnt(0)"
      : "=&v"(a), "=&v"(b) : "v"(p0), "v"(p1) : "memory");
}

// ---------------- generic transpose: out[c][r] = in[r][c0+c] ----------------
__global__ __launch_bounds__(256)
void k_transpose(const float* __restrict__ in, int R, int Ctot, int c0,
                 float* __restrict__ out) {
  __shared__ float tile[32][33];
  int ct = blockIdx.x * 32;
  int rt = blockIdx.y * 32;
  int lx = threadIdx.x & 31, ly = threadIdx.x >> 5;
#pragma unroll
  for (int i = 0; i < 32; i += 8)
    tile[ly + i][lx] = in[(long)(rt + ly + i) * Ctot + c0 + ct + lx];
  __syncthreads();
#pragma unroll
  for (int i = 0; i < 32; i += 8)
    out[(long)(ct + ly + i) * R + rt + lx] = tile[lx][ly + i];
}

// ---- pack fp32 weights (embed GEMM): out[(k4)*1536*4 + j*4 + q] ----
__global__ __launch_bounds__(256)
void k_pack4(const float* __restrict__ in, int rs, int c0,
             float* __restrict__ out, int k4off) {
  int jl = threadIdx.x & 15, k4l = threadIdx.x >> 4;
  int j = blockIdx.y * 16 + jl;
  int k4 = blockIdx.x * 16 + k4l;
  float4 v = *(const float4*)(in + (long)j * rs + c0 + k4 * 4);
  *(float4*)(out + ((long)(k4 + k4off) * H3z + j) * 4) = v;
}

// ---- pack recurrent weights to bf16: out[(k8+k8off)*1536 + j][8] ----
__global__ __launch_bounds__(256)
void k_packbf(const float* __restrict__ in, int rs, int c0,
              unsigned short* __restrict__ out, int k8off) {
  int jl = threadIdx.x & 31, k8l = threadIdx.x >> 5;  // 32 j x 8 k8
  int j = blockIdx.y * 32 + jl;
  int k8 = blockIdx.x * 8 + k8l;
  const float* src = in + (long)j * rs + c0 + k8 * 8;
  float4 a = *(const float4*)src;
  float4 b = *(const float4*)(src + 4);
  u16x8 o;
  o[0] = f2bf(a.x); o[1] = f2bf(a.y); o[2] = f2bf(a.z); o[3] = f2bf(a.w);
  o[4] = f2bf(b.x); o[5] = f2bf(b.y); o[6] = f2bf(b.z); o[7] = f2bf(b.w);
  *(u16x8*)(out + ((long)(k8 + k8off) * H3z + j) * 8) = o;
}

// -------- embed + input-GEMM with packed fp32 weights W4[k4][1536][4], K=256
__global__ __launch_bounds__(256)
void k_embed_gi(const int* __restrict__ toks, const float* __restrict__ emb,
                const float* __restrict__ W4, const float* __restrict__ bias,
                float* __restrict__ G) {
  __shared__ float se[16][Ez];
  int jg = blockIdx.x % 24;
  int rg = blockIdx.x / 24;
  int r0 = rg * 16;
  int tid = threadIdx.x;
  for (int c = tid; c < 16 * Ez; c += 256) {
    int rl = c >> 8;
    int k = c & 255;
    int r = r0 + rl;
    int tok = toks[(r & 31) * 64 + (r >> 5)];
    se[rl][k] = emb[(long)tok * Ez + k];
  }
  __syncthreads();
  int jj = tid & 63, rq = tid >> 6;
  int j = jg * 64 + jj;
  float a0 = 0.f, a1 = 0.f, a2 = 0.f, a3 = 0.f;
#pragma unroll 4
  for (int k4 = 0; k4 < 64; ++k4) {
    float4 w = *(const float4*)(W4 + ((long)k4 * H3z + j) * 4);
    const float* s0 = &se[rq * 4 + 0][k4 * 4];
    const float* s1 = &se[rq * 4 + 1][k4 * 4];
    const float* s2 = &se[rq * 4 + 2][k4 * 4];
    const float* s3 = &se[rq * 4 + 3][k4 * 4];
    a0 = fmaf(s0[3], w.w, fmaf(s0[2], w.z, fmaf(s0[1], w.y, fmaf(s0[0], w.x, a0))));
    a1 = fmaf(s1[3], w.w, fmaf(s1[2], w.z, fmaf(s1[1], w.y, fmaf(s1[0], w.x, a1))));
    a2 = fmaf(s2[3], w.w, fmaf(s2[2], w.z, fmaf(s2[1], w.y, fmaf(s2[0], w.x, a2))));
    a3 = fmaf(s3[3], w.w, fmaf(s3[2], w.z, fmaf(s3[1], w.y, fmaf(s3[0], w.x, a3))));
  }
  float bj = bias[j];
  G[(long)(r0 + rq * 4 + 0) * H3z + j] = a0 + bj;
  G[(long)(r0 + rq * 4 + 1) * H3z + j] = a1 + bj;
  G[(long)(r0 + rq * 4 + 2) * H3z + j] = a2 + bj;
  G[(long)(r0 + rq * 4 + 3) * H3z + j] = a3 + bj;
}

// ---------------- fp32 -> bf16 convert ----------------
__global__ void k_f2bf(const float* __restrict__ in, unsigned short* __restrict__ out, long n4) {
  long i = (long)blockIdx.x * blockDim.x + threadIdx.x;
  long stride = (long)gridDim.x * blockDim.x;
  for (; i < n4; i += stride) {
    float4 v = ((const float4*)in)[i];
    ushort4 o;
    o.x = f2bf(v.x); o.y = f2bf(v.y); o.z = f2bf(v.z); o.w = f2bf(v.w);
    ((ushort4*)out)[i] = o;
  }
}

// ================= persistent recurrence kernel =================
struct PP {
  const float* giEnc;
  const float* giDec;
  const unsigned short* W8e0;    // [64 k8][1536][8]   enc whh0
  const unsigned short* W8e1;    // [128 k8][1536][8]  enc wih1 | whh1
  const unsigned short* W8d0x;   // [64]  dec wih0 ctx-cols
  const unsigned short* W8d0h;   // [64]  dec whh0
  const unsigned short* W8d1x;   // [64]  dec wih1
  const unsigned short* W8d1h;   // [64]  dec whh1
  const float* enc_bhh0;
  const float* enc_bih1;
  const float* enc_bhh1;
  const float* dec_bhh0;
  const float* dec_bih1;
  const float* dec_bhh1;
  const float* wtAttn;
  const int* src;
  float* h0; float* h1; float* d0; float* d1; float* ctx;  // 2-slot sc state
  float* hpd0; float* hpd1;      // 2-slot [3][32][512] h-part partials (sc)
  float* encOut;                 // sc [32][64][512]
  unsigned short* keNb;          // bf16 [32*64][512] normal-cached
  unsigned short* encNb;         // bf16 [32*64][512] normal-cached
  unsigned* flags;
  unsigned short* d1ctxBf;
};

// Grid barrier: drain sc stores, publish flag (sc), wave0 spins on sc flags.
__device__ __forceinline__ void gsync(unsigned* flags, unsigned ph) {
  wait_vm0();
  __syncthreads();
  int tid = threadIdx.x;
  if (tid == 0) st_flag(&flags[blockIdx.x], ph);
  if (tid < 64) {
    const unsigned* p0 = &flags[tid];
    const unsigned* p1 = &flags[tid + 64];
    for (;;) {
      unsigned f0, f1;
      ld2u_sc(p0, p1, f0, f1);
      if (!__any(f0 < ph || f1 < ph)) break;
      __builtin_amdgcn_s_sleep(1);
    }
  }
  __syncthreads();
}

// ---- shared weight-pipeline pieces: 8 waves, wave kq owns a k8-row range ----
#define W_PREFETCH_G0(Wr0, wA)                                        \
  { const u16x8* Wr = (Wr0);                                          \
    wA[0][0] = Wr[0];    wA[0][1] = Wr[512];  wA[0][2] = Wr[1024];    \
    wA[1][0] = Wr[1536]; wA[1][1] = Wr[2048]; wA[1][2] = Wr[2560]; }

// full GRU cell (encoder): 8 waves; HASX: waves 0-3 x-part, 4-7 h-part.
template <int HASX>
__device__ __forceinline__ void gru_full(
    int blkid, const unsigned short* __restrict__ W8,
    const float* __restrict__ gi, const float* __restrict__ bih,
    const float* __restrict__ bhh,
    const float* __restrict__ xin, const float* __restrict__ hin,
    float* __restrict__ hout, float* __restrict__ fout, long fstride,
    float* smem) {
  float* sh = smem;
  float* sx = smem + 2048;
  float* part = smem + 4096;
  const int jg = blkid & 7, bg = blkid >> 3;
  const int tid = threadIdx.x;
  const int l = tid & 63, kq = tid >> 6;
  const int j = jg * 64 + l;
  constexpr int Q8 = HASX ? 16 : 8;
  constexpr int G8 = Q8 / 2;
  const u16x8* Wr0 = (const u16x8*)W8 + (long)(kq * Q8) * H3z + j;

  u16x8 wA[2][3], wB[2][3];
  W_PREFETCH_G0(Wr0, wA);
  float gir = 0.f, giz = 0.f, gin = 0.f;
  if (tid < 256) {
    const int b4 = tid >> 6, jc = tid & 63;
    const int b = bg * 4 + b4, jj = jg * 64 + jc;
    if (gi) {
      gir = gi[(long)b * H3z + jj];
      giz = gi[(long)b * H3z + 512 + jj];
      gin = gi[(long)b * H3z + 1024 + jj];
    }
    if (bih) { gir += bih[jj]; giz += bih[512 + jj]; gin += bih[1024 + jj]; }
  }
  {
    const f32x4* hp = (const f32x4*)(hin + bg * 2048);
    f32x4 a = ld_sc_nw(hp + tid);
    if (HASX) {
      const f32x4* xp = (const f32x4*)(xin + bg * 2048);
      f32x4 c = ld_sc_nw(xp + tid);
      wait_vm0();
      ((f32x4*)sh)[tid] = a;
      ((f32x4*)sx)[tid] = c;
    } else {
      wait_vm0();
      ((f32x4*)sh)[tid] = a;
    }
  }
  __syncthreads();
  const float* vb;
  if (HASX) vb = (kq < 4) ? (sx + kq * 128) : (sh + (kq - 4) * 128);
  else      vb = sh + kq * 64;
  float pr[4] = {0, 0, 0, 0}, pz[4] = {0, 0, 0, 0}, pn[4] = {0, 0, 0, 0};
  auto loadg = [&](u16x8 (&w)[2][3], int g) {
    const u16x8* Wr = Wr0 + (long)(2 * g) * H3z;
    w[0][0] = Wr[0];    w[0][1] = Wr[512];  w[0][2] = Wr[1024];
    w[1][0] = Wr[1536]; w[1][1] = Wr[2048]; w[1][2] = Wr[2560];
  };
  auto compg = [&](u16x8 (&w)[2][3], int g) {
#pragma unroll
    for (int r = 0; r < 2; ++r) {
      const int kk = 2 * g + r;
      float f0[8], f1[8], f2[8];
#pragma unroll
      for (int e = 0; e < 8; ++e) {
        f0[e] = bf2f(w[r][0][e]); f1[e] = bf2f(w[r][1][e]); f2[e] = bf2f(w[r][2][e]);
      }
#pragma unroll
      for (int b4 = 0; b4 < 4; ++b4) {
        const float* v = vb + kk * 8 + b4 * 512;
        f32x4 v0 = *(const f32x4*)v;
        f32x4 v1 = *(const f32x4*)(v + 4);
#pragma unroll
        for (int e = 0; e < 4; ++e) {
          pr[b4] = fmaf(v0[e], f0[e], pr[b4]);
          pz[b4] = fmaf(v0[e], f1[e], pz[b4]);
          pn[b4] = fmaf(v0[e], f2[e], pn[b4]);
        }
#pragma unroll
        for (int e = 0; e < 4; ++e) {
          pr[b4] = fmaf(v1[e], f0[4 + e], pr[b4]);
          pz[b4] = fmaf(v1[e], f1[4 + e], pz[b4]);
          pn[b4] = fmaf(v1[e], f2[4 + e], pn[b4]);
        }
      }
    }
  };
#pragma unroll
  for (int g = 0; g < G8; g += 2) {
    if (g + 1 < G8) loadg(wB, g + 1);
    compg(wA, g);
    if (g + 2 < G8) loadg(wA, g + 2);
    if (g + 1 < G8) compg(wB, g + 1);
  }
#pragma unroll
  for (int b4 = 0; b4 < 4; ++b4) {
    part[((0 * 4 + b4) * 8 + kq) * 64 + l] = pr[b4];
    part[((1 * 4 + b4) * 8 + kq) * 64 + l] = pz[b4];
    part[((2 * 4 + b4) * 8 + kq) * 64 + l] = pn[b4];
  }
  __syncthreads();
  if (tid < 256) {
    const int b4 = tid >> 6, jc = tid & 63;
    const int b = bg * 4 + b4;
    const int jj = jg * 64 + jc;
    float sr = 0.f, sz = 0.f, snx = 0.f, snh = 0.f;
#pragma unroll
    for (int q = 0; q < 8; ++q) {
      sr += part[((0 * 4 + b4) * 8 + q) * 64 + jc];
      sz += part[((1 * 4 + b4) * 8 + q) * 64 + jc];
      float pnq = part[((2 * 4 + b4) * 8 + q) * 64 + jc];
      if (HASX && q < 4) snx += pnq; else snh += pnq;
    }
    float rv = 1.f / (1.f + __expf(-(gir + sr + bhh[jj])));
    float zv = 1.f / (1.f + __expf(-(giz + sz + bhh[512 + jj])));
    float nv = tanhf(gin + snx + rv * (snh + bhh[1024 + jj]));
    float hv = sh[b4 * 512 + jj];
    float hp2 = (1.f - zv) * nv + zv * hv;
    st_sc(hout + (long)b * 512 + jj, hp2);
    if (fout) st_sc(fout + (long)b * fstride + jj, hp2);
  }
}

// x-part + combine (decoder): k=512 x-GEMV; h-part read from hp[3][32][512].
__device__ __forceinline__ void gru_xpart(
    int blkid, const unsigned short* __restrict__ Wx,
    const float* __restrict__ gi, const float* __restrict__ bih,
    const float* __restrict__ bhh,
    const float* __restrict__ xin, const float* __restrict__ hprev,
    const float* __restrict__ hp, float* __restrict__ hout,
    unsigned short* __restrict__ bfout, float* smem) {
  float* sx = smem;
  float* part = smem + 4096;
  const int jg = blkid & 7, bg = blkid >> 3;
  const int tid = threadIdx.x;
  const int l = tid & 63, kq = tid >> 6;
  const int j = jg * 64 + l;
  const u16x8* Wr0 = (const u16x8*)Wx + (long)(kq * 8) * H3z + j;
  u16x8 wA[2][3], wB[2][3];
  W_PREFETCH_G0(Wr0, wA);
  float gir = 0.f, giz = 0.f, gin = 0.f;
  if (tid < 256) {
    const int b4 = tid >> 6, jc = tid & 63;
    const int b = bg * 4 + b4, jj = jg * 64 + jc;
    if (gi) {
      gir = gi[(long)b * H3z + jj];
      giz = gi[(long)b * H3z + 512 + jj];
      gin = gi[(long)b * H3z + 1024 + jj];
    }
    if (bih) { gir += bih[jj]; giz += bih[512 + jj]; gin += bih[1024 + jj]; }
  }
  {
    const f32x4* xp = (const f32x4*)(xin + bg * 2048);
    f32x4 a = ld_sc_nw(xp + tid);
    wait_vm0();
    ((f32x4*)sx)[tid] = a;
  }
  __syncthreads();
  const float* vb = sx + kq * 64;
  float pr[4] = {0, 0, 0, 0}, pz[4] = {0, 0, 0, 0}, pn[4] = {0, 0, 0, 0};
  auto loadg = [&](u16x8 (&w)[2][3], int g) {
    const u16x8* Wr = Wr0 + (long)(2 * g) * H3z;
    w[0][0] = Wr[0];    w[0][1] = Wr[512];  w[0][2] = Wr[1024];
    w[1][0] = Wr[1536]; w[1][1] = Wr[2048]; w[1][2] = Wr[2560];
  };
  auto compg = [&](u16x8 (&w)[2][3], int g) {
#pragma unroll
    for (int r = 0; r < 2; ++r) {
      const int kk = 2 * g + r;
      float f0[8], f1[8], f2[8];
#pragma unroll
      for (int e = 0; e < 8; ++e) {
        f0[e] = bf2f(w[r][0][e]); f1[e] = bf2f(w[r][1][e]); f2[e] = bf2f(w[r][2][e]);
      }
#pragma unroll
      for (int b4 = 0; b4 < 4; ++b4) {
        const float* v = vb + kk * 8 + b4 * 512;
        f32x4 v0 = *(const f32x4*)v;
        f32x4 v1 = *(const f32x4*)(v + 4);
#pragma unroll
        for (int e = 0; e < 4; ++e) {
          pr[b4] = fmaf(v0[e], f0[e], pr[b4]);
          pz[b4] = fmaf(v0[e], f1[e], pz[b4]);
          pn[b4] = fmaf(v0[e], f2[e], pn[b4]);
        }
#pragma unroll
        for (int e = 0; e < 4; ++e) {
          pr[b4] = fmaf(v1[e], f0[4 + e], pr[b4]);
          pz[b4] = fmaf(v1[e], f1[4 + e], pz[b4]);
          pn[b4] = fmaf(v1[e], f2[4 + e], pn[b4]);
        }
      }
    }
  };
#pragma unroll
  for (int g = 0; g < 4; g += 2) {
    loadg(wB, g + 1);
    compg(wA, g);
    if (g + 2 < 4) loadg(wA, g + 2);
    compg(wB, g + 1);
  }
#pragma unroll
  for (int b4 = 0; b4 < 4; ++b4) {
    part[((0 * 4 + b4) * 8 + kq) * 64 + l] = pr[b4];
    part[((1 * 4 + b4) * 8 + kq) * 64 + l] = pz[b4];
    part[((2 * 4 + b4) * 8 + kq) * 64 + l] = pn[b4];
  }
  __syncthreads();
  if (tid < 256) {
    const int b4 = tid >> 6, jc = tid & 63;
    const int b = bg * 4 + b4;
    const int jj = jg * 64 + jc;
    float hr, hz, hn, hv;
    ld4f_sc(hp + (long)(0 * 32 + b) * 512 + jj, hp + (long)(1 * 32 + b) * 512 + jj,
            hp + (long)(2 * 32 + b) * 512 + jj, hprev + (long)b * 512 + jj,
            hr, hz, hn, hv);
    float sr = 0.f, sz = 0.f, sn = 0.f;
#pragma unroll
    for (int q = 0; q < 8; ++q) {
      sr += part[((0 * 4 + b4) * 8 + q) * 64 + jc];
      sz += part[((1 * 4 + b4) * 8 + q) * 64 + jc];
      sn += part[((2 * 4 + b4) * 8 + q) * 64 + jc];
    }
    float rv = 1.f / (1.f + __expf(-(gir + sr + hr + bhh[jj])));
    float zv = 1.f / (1.f + __expf(-(giz + sz + hz + bhh[512 + jj])));
    float nv = tanhf(gin + sn + rv * (hn + bhh[1024 + jj]));
    float hp2 = (1.f - zv) * nv + zv * hv;
    st_sc(hout + (long)b * 512 + jj, hp2);
    if (bfout) bfout[(long)b * 1024 + jj] = f2bf(hp2);
  }
}

// h-part producer: hpOut[g][b][jj] = (Whh · hin)[g*512+jj] for batch b (no bias)
__device__ __forceinline__ void gru_hpart(
    int blkid, const unsigned short* __restrict__ Wh,
    const float* __restrict__ hin, float* __restrict__ hpOut, float* smem) {
  float* sh = smem;
  float* part = smem + 4096;
  const int jg = blkid & 7, bg = blkid >> 3;
  const int tid = threadIdx.x;
  const int l = tid & 63, kq = tid >> 6;
  const int j = jg * 64 + l;
  const u16x8* Wr0 = (const u16x8*)Wh + (long)(kq * 8) * H3z + j;
  u16x8 wA[2][3], wB[2][3];
  W_PREFETCH_G0(Wr0, wA);
  {
    const f32x4* hp = (const f32x4*)(hin + bg * 2048);
    f32x4 a = ld_sc_nw(hp + tid);
    wait_vm0();
    ((f32x4*)sh)[tid] = a;
  }
  __syncthreads();
  const float* vb = sh + kq * 64;
  float pr[4] = {0, 0, 0, 0}, pz[4] = {0, 0, 0, 0}, pn[4] = {0, 0, 0, 0};
  auto loadg = [&](u16x8 (&w)[2][3], int g) {
    const u16x8* Wr = Wr0 + (long)(2 * g) * H3z;
    w[0][0] = Wr[0];    w[0][1] = Wr[512];  w[0][2] = Wr[1024];
    w[1][0] = Wr[1536]; w[1][1] = Wr[2048]; w[1][2] = Wr[2560];
  };
  auto compg = [&](u16x8 (&w)[2][3], int g) {
#pragma unroll
    for (int r = 0; r < 2; ++r) {
      const int kk = 2 * g + r;
      float f0[8], f1[8], f2[8];
#pragma unroll
      for (int e = 0; e < 8; ++e) {
        f0[e] = bf2f(w[r][0][e]); f1[e] = bf2f(w[r][1][e]); f2[e] = bf2f(w[r][2][e]);
      }
#pragma unroll
      for (int b4 = 0; b4 < 4; ++b4) {
        const float* v = vb + kk * 8 + b4 * 512;
        f32x4 v0 = *(const f32x4*)v;
        f32x4 v1 = *(const f32x4*)(v + 4);
#pragma unroll
        for (int e = 0; e < 4; ++e) {
          pr[b4] = fmaf(v0[e], f0[e], pr[b4]);
          pz[b4] = fmaf(v0[e], f1[e], pz[b4]);
          pn[b4] = fmaf(v0[e], f2[e], pn[b4]);
        }
#pragma unroll
        for (int e = 0; e < 4; ++e) {
          pr[b4] = fmaf(v1[e], f0[4 + e], pr[b4]);
          pz[b4] = fmaf(v1[e], f1[4 + e], pz[b4]);
          pn[b4] = fmaf(v1[e], f2[4 + e], pn[b4]);
        }
      }
    }
  };
#pragma unroll
  for (int g = 0; g < 4; g += 2) {
    loadg(wB, g + 1);
    compg(wA, g);
    if (g + 2 < 4) loadg(wA, g + 2);
    compg(wB, g + 1);
  }
#pragma unroll
  for (int b4 = 0; b4 < 4; ++b4) {
    part[((0 * 4 + b4) * 8 + kq) * 64 + l] = pr[b4];
    part[((1 * 4 + b4) * 8 + kq) * 64 + l] = pz[b4];
    part[((2 * 4 + b4) * 8 + kq) * 64 + l] = pn[b4];
  }
  __syncthreads();
  if (tid < 256) {
    const int b4 = tid >> 6, jc = tid & 63;
    const int b = bg * 4 + b4;
    const int jj = jg * 64 + jc;
    float s0 = 0.f, s1 = 0.f, s2 = 0.f;
#pragma unroll
    for (int q = 0; q < 8; ++q) {
      s0 += part[((0 * 4 + b4) * 8 + q) * 64 + jc];
      s1 += part[((1 * 4 + b4) * 8 + q) * 64 + jc];
      s2 += part[((2 * 4 + b4) * 8 + q) * 64 + jc];
    }
    st_sc(hpOut + (long)(0 * 32 + b) * 512 + jj, s0);
    st_sc(hpOut + (long)(1 * 32 + b) * 512 + jj, s1);
    st_sc(hpOut + (long)(2 * 32 + b) * 512 + jj, s2);
  }
}

// ke + bf16 republish (512 threads): block (b=blk&31, sq=blk>>5) -> 16 rows
__device__ void ke_phase(int blk, const float* __restrict__ encOut,
                         const float* __restrict__ attn_wT,
                         unsigned short* __restrict__ keNb,
                         unsigned short* __restrict__ encNb, float* smem) {
  int b = blk & 31, sq = blk >> 5;
  long r0 = (long)b * 64 + sq * 16;
  int tid = threadIdx.x;
  {
    const f32x4* ep = (const f32x4*)(encOut + r0 * 512);
    f32x4 v[4];
#pragma unroll
    for (int u = 0; u < 4; ++u) v[u] = ld_sc_nw(ep + tid + u * 512);
    wait_vm0();
#pragma unroll
    for (int u = 0; u < 4; ++u) ((f32x4*)smem)[tid + u * 512] = v[u];
  }
  __syncthreads();
  {
    u16x8 o0, o1;
    const float* s = smem + tid * 16;
#pragma unroll
    for (int e = 0; e < 8; ++e) { o0[e] = f2bf(s[e]); o1[e] = f2bf(s[8 + e]); }
    *(u16x8*)(encNb + r0 * 512 + tid * 16) = o0;
    *(u16x8*)(encNb + r0 * 512 + tid * 16 + 8) = o1;
  }
  int jj = tid & 63, rq = tid >> 6;  // 8 groups x 2 rows
  float acc[2][8];
#pragma unroll
  for (int r = 0; r < 2; ++r)
#pragma unroll
    for (int jc = 0; jc < 8; ++jc) acc[r][jc] = 0.f;
#pragma unroll 2
  for (int k = 0; k < 512; ++k) {
    float w[8];
#pragma unroll
    for (int jc = 0; jc < 8; ++jc) w[jc] = attn_wT[(long)k * 512 + jc * 64 + jj];
    float e0 = smem[(rq * 2) * 512 + k], e1 = smem[(rq * 2 + 1) * 512 + k];
#pragma unroll
    for (int jc = 0; jc < 8; ++jc) {
      acc[0][jc] = fmaf(e0, w[jc], acc[0][jc]);
      acc[1][jc] = fmaf(e1, w[jc], acc[1][jc]);
    }
  }
#pragma unroll
  for (int r = 0; r < 2; ++r)
#pragma unroll
    for (int jc = 0; jc < 8; ++jc)
      keNb[(r0 + rq * 2 + r) * 512 + jc * 64 + jj] = f2bf(acc[r][jc]);
}

__device__ void attn_phase(int b, const float* __restrict__ d1,
                           const unsigned short* __restrict__ keNb,
                           const unsigned short* __restrict__ encNb,
                           const int* __restrict__ src,
                           float* __restrict__ ctxn,
                           unsigned short* __restrict__ bfctx, float* smem) {
  float* sd = smem;
  float* sc = smem + 512;
  int tid = threadIdx.x;
  {
    float a;
    ld1f_sc(d1 + b * 512 + tid, a);
    sd[tid] = a;
  }
  __syncthreads();
  int s = tid >> 3, q = tid & 7;
  const u16x8* kp = (const u16x8*)(keNb + ((long)b * 64 + s) * 512 + q * 64);
  const float* dp = sd + q * 64;
  float p = 0.f;
#pragma unroll
  for (int e = 0; e < 8; ++e) {
    u16x8 kv = kp[e];
#pragma unroll
    for (int i = 0; i < 8; ++i) p = fmaf(bf2f(kv[i]), dp[e * 8 + i], p);
  }
  p += __shfl_xor(p, 1);
  p += __shfl_xor(p, 2);
  p += __shfl_xor(p, 4);
  if (q == 0) sc[s] = (src[b * 64 + s] == 0) ? -1e9f : p;
  __syncthreads();
  if (tid < 64) {
    float v = sc[tid];
    float m = v;
    for (int o = 32; o; o >>= 1) m = fmaxf(m, __shfl_xor(m, o));
    float e = __expf(v - m);
    float sum = e;
    for (int o = 32; o; o >>= 1) sum += __shfl_xor(sum, o);
    sc[tid] = e / sum;
  }
  __syncthreads();
  float a0 = 0.f;
  const unsigned short* er = encNb + (long)b * 64 * 512 + tid;
#pragma unroll 8
  for (int s2 = 0; s2 < 64; ++s2) a0 = fmaf(sc[s2], bf2f(er[(long)s2 * 512]), a0);
  st_sc(ctxn + b * 512 + tid, a0);
  bfctx[b * 1024 + tid] = f2bf(a0);
}

__global__ __launch_bounds__(512, 2) void k_persist(PP P) {
  __shared__ float smem[10240];  // 40KB: sh 8K | sx 8K | part 24K
  int blk = blockIdx.x;
  unsigned ph = 0;
  // ---- encoder: layer1 pipelined one step behind layer0 ----
  for (int i = 0; i < Sz + 1; ++i) {
    if (blk < 64) {
      if (i < Sz)
        gru_full<0>(blk, P.W8e0, P.giEnc + (long)i * 49152, nullptr, P.enc_bhh0,
                    nullptr, P.h0 + (i & 1) * 16384, P.h0 + ((i + 1) & 1) * 16384,
                    nullptr, 0, smem);
    } else if (i >= 1) {
      int t = i - 1;
      gru_full<1>(blk - 64, P.W8e1, nullptr, P.enc_bih1, P.enc_bhh1,
                  P.h0 + (i & 1) * 16384, P.h1 + (t & 1) * 16384,
                  P.h1 + ((t + 1) & 1) * 16384,
                  P.encOut + (long)t * 512, (long)Sz * 512, smem);
    }
    gsync(P.flags, ++ph);
  }
  // ---- ke (bf16 republish) ----
  ke_phase(blk, P.encOut, P.wtAttn, P.keNb, P.encNb, smem);
  gsync(P.flags, ++ph);
  // ---- hpd0 for t=0 (from enc h0 final, slot 0) ----
  if (blk < 64) gru_hpart(blk, P.W8d0h, P.h0, P.hpd0, smem);
  gsync(P.flags, ++ph);
  // ---- decoder: gate-split, 3 phases/step ----
  for (int t = 0; t < Tdec; ++t) {
    int cs = t & 1, ps = cs ^ 1;
    const float* d0prev = (t == 0) ? P.h0 : P.d0 + ps * 16384;
    const float* d1prev = (t == 0) ? P.h1 : P.d1 + ps * 16384;
    // P1: d0^t = xpart(ctx^{t-1}) + hpd0^t ; blocks 64+: hpd1^t = Whh1 d1^{t-1}
    if (blk < 64)
      gru_xpart(blk, P.W8d0x, P.giDec + (long)t * 49152, nullptr, P.dec_bhh0,
                P.ctx + ps * 16384, d0prev, P.hpd0 + cs * 49152,
                P.d0 + cs * 16384, nullptr, smem);
    else
      gru_hpart(blk - 64, P.W8d1h, d1prev, P.hpd1 + cs * 49152, smem);
    gsync(P.flags, ++ph);
    // P2: d1^t = xpart(d0^t) + hpd1^t ; blocks 64+: hpd0^{t+1} = Whh0 d0^t
    if (blk < 64)
      gru_xpart(blk, P.W8d1x, nullptr, P.dec_bih1, P.dec_bhh1,
                P.d0 + cs * 16384, d1prev, P.hpd1 + cs * 49152,
                P.d1 + cs * 16384, P.d1ctxBf + (long)t * 32768, smem);
    else
      gru_hpart(blk - 64, P.W8d0h, P.d0 + cs * 16384, P.hpd0 + ps * 49152, smem);
    gsync(P.flags, ++ph);
    // P3: attention
    if (blk < 32)
      attn_phase(blk, P.d1 + cs * 16384, P.keNb, P.encNb, P.src,
                 P.ctx + cs * 16384, P.d1ctxBf + (long)t * 32768 + 512, smem);
    gsync(P.flags, ++ph);
  }
}

// ---------------- final bf16 MFMA GEMM (validated) ----------------
__global__ __launch_bounds__(256)
void k_out_gemm(const unsigned short* __restrict__ A, const unsigned short* __restrict__ Bw,
                const float* __restrict__ bias, float* __restrict__ out) {
  __shared__ __align__(16) char lds[32768];
  int bid = blockIdx.x;
  int bm = bid & 15, bn = bid >> 4;
  long m0 = (long)bm * 128, n0 = (long)bn * 128;
  int tid = threadIdx.x, lane = tid & 63, wid = tid >> 6;
  int wm = wid >> 1, wn = wid & 1;
  floatx4 acc[4][4];
#pragma unroll
  for (int i = 0; i < 4; i++)
#pragma unroll
    for (int jx = 0; jx < 4; jx++) acc[i][jx] = (floatx4){0.f, 0.f, 0.f, 0.f};

  int rl = lane >> 3;
  int kb = (((lane & 7) ^ rl) << 4);

  for (int kt = 0; kt < 16; ++kt) {
    long kbyte0 = (long)kt * 128;
#pragma unroll
    for (int q = 0; q < 4; ++q) {
      int c = wid * 4 + q;
      int row = c * 8 + rl;
      const char* ga = (const char*)A + (m0 + row) * 2048 + kbyte0 + kb;
      const char* gb = (const char*)Bw + (n0 + row) * 2048 + kbyte0 + kb;
      __builtin_amdgcn_global_load_lds(
          (const __attribute__((address_space(1))) void*)ga,
          (__attribute__((address_space(3))) void*)(lds + (c << 10)), 16, 0, 0);
      __builtin_amdgcn_global_load_lds(
          (const __attribute__((address_space(1))) void*)gb,
          (__attribute__((address_space(3))) void*)(lds + 16384 + (c << 10)), 16, 0, 0);
    }
    asm volatile("s_waitcnt vmcnt(0)" ::: "memory");
    __syncthreads();
#pragma unroll
    for (int kk = 0; kk < 2; ++kk) {
      shortx8 af[4], bf[4];
#pragma unroll
      for (int f = 0; f < 4; ++f) {
        int rowA = wm * 64 + f * 16 + (lane & 15);
        int cbA = (kk * 64 + ((lane >> 4) << 4)) ^ ((rowA & 7) << 4);
        af[f] = *(const shortx8*)(lds + rowA * 128 + cbA);
        int rowB = wn * 64 + f * 16 + (lane & 15);
        int cbB = (kk * 64 + ((lane >> 4) << 4)) ^ ((rowB & 7) << 4);
        bf[f] = *(const shortx8*)(lds + 16384 + rowB * 128 + cbB);
      }
#pragma unroll
      for (int mf = 0; mf < 4; ++mf)
#pragma unroll
        for (int nf = 0; nf < 4; ++nf)
          acc[mf][nf] = __builtin_amdgcn_mfma_f32_16x16x32_bf16(af[mf], bf[nf], acc[mf][nf], 0, 0, 0);
    }
    __syncthreads();
  }
#pragma unroll
  for (int mf = 0; mf < 4; ++mf) {
#pragma unroll
    for (int nf = 0; nf < 4; ++nf) {
      long gn = n0 + wn * 64 + nf * 16 + (lane & 15);
      float bb = bias[gn];
#pragma unroll
      for (int r = 0; r < 4; ++r) {
        long gm = m0 + wm * 64 + mf * 16 + ((lane >> 4) * 4) + r;
        if (gm < (long)Tdec * Bz) {
          long t = gm >> 5, b = gm & 31;
          out[(b * Tdec + t) * (long)Vz + gn] = acc[mf][nf][r] + bb;
        }
      }
    }
  }
}

extern "C" void kernel_launch(void* const* d_in, const int* in_sizes, int n_in,
                              void* d_out, int out_size, void* d_ws, size_t ws_size,
                              hipStream_t stream) {
  const int*   src      = (const int*)d_in[0];
  const int*   tgt      = (const int*)d_in[1];
  const float* enc_emb  = (const float*)d_in[2];
  const float* enc_wih0 = (const float*)d_in[3];
  const float* enc_whh0 = (const float*)d_in[4];
  const float* enc_bih0 = (const float*)d_in[5];
  const float* enc_bhh0 = (const float*)d_in[6];
  const float* enc_wih1 = (const float*)d_in[7];
  const float* enc_whh1 = (const float*)d_in[8];
  const float* enc_bih1 = (const float*)d_in[9];
  const float* enc_bhh1 = (const float*)d_in[10];
  const float* dec_emb  = (const float*)d_in[11];
  const float* dec_wih0 = (const float*)d_in[12];
  const float* dec_whh0 = (const float*)d_in[13];
  const float* dec_bih0 = (const float*)d_in[14];
  const float* dec_bhh0 = (const float*)d_in[15];
  const float* dec_wih1 = (const float*)d_in[16];
  const float* dec_whh1 = (const float*)d_in[17];
  const float* dec_bih1 = (const float*)d_in[18];
  const float* dec_bhh1 = (const float*)d_in[19];
  const float* attn_w   = (const float*)d_in[20];
  const float* out_w    = (const float*)d_in[21];
  const float* out_b    = (const float*)d_in[22];
  float* out = (float*)d_out;

  char* ws = (char*)d_ws;
  size_t off = 0;
  auto alloc = [&](size_t bytes) -> char* {
    char* p = ws + off;
    off += (bytes + 255) & ~(size_t)255;
    return p;
  };
  float* W4embE = (float*)alloc((size_t)Ez * H3z * 4);
  float* W4embD = (float*)alloc((size_t)Ez * H3z * 4);
  unsigned short* W8e0  = (unsigned short*)alloc((size_t)64 * H3z * 8 * 2);
  unsigned short* W8e1  = (unsigned short*)alloc((size_t)128 * H3z * 8 * 2);
  unsigned short* W8d0x = (unsigned short*)alloc((size_t)64 * H3z * 8 * 2);
  unsigned short* W8d0h = (unsigned short*)alloc((size_t)64 * H3z * 8 * 2);
  unsigned short* W8d1x = (unsigned short*)alloc((size_t)64 * H3z * 8 * 2);
  unsigned short* W8d1h = (unsigned short*)alloc((size_t)64 * H3z * 8 * 2);
  float* wtAttn = (float*)alloc((size_t)Hz * Hz * 4);
  float* giEnc  = (float*)alloc((size_t)Sz * Bz * H3z * 4);
  float* giDec  = (float*)alloc((size_t)Tdec * Bz * H3z * 4);
  float* encOut = (float*)alloc((size_t)Bz * Sz * Hz * 4);
  unsigned short* keNb  = (unsigned short*)alloc((size_t)Bz * Sz * Hz * 2);
  unsigned short* encNb = (unsigned short*)alloc((size_t)Bz * Sz * Hz * 2);
  float* h0buf  = (float*)alloc((size_t)2 * Bz * Hz * 4);
  float* h1buf  = (float*)alloc((size_t)2 * Bz * Hz * 4);
  float* d0buf  = (float*)alloc((size_t)2 * Bz * Hz * 4);
  float* d1buf  = (float*)alloc((size_t)2 * Bz * Hz * 4);
  float* ctxbuf = (float*)alloc((size_t)2 * Bz * Hz * 4);
  float* hpd0   = (float*)alloc((size_t)2 * 3 * Bz * Hz * 4);
  float* hpd1   = (float*)alloc((size_t)2 * 3 * Bz * Hz * 4);
  unsigned short* d1ctxBf = (unsigned short*)alloc((size_t)2048 * 1024 * 2);
  unsigned short* outwBf  = (unsigned short*)alloc((size_t)Vz * 1024 * 2);
  unsigned* flags = (unsigned*)alloc(NB * 4);
  if (off > ws_size) return;

  dim3 tb(256);
  k_pack4<<<dim3(4, 96), tb, 0, stream>>>(enc_wih0, Ez, 0, W4embE, 0);
  k_pack4<<<dim3(4, 96), tb, 0, stream>>>(dec_wih0, Ez + Hz, 0, W4embD, 0);
  k_packbf<<<dim3(8, 48), tb, 0, stream>>>(enc_whh0, Hz, 0, W8e0, 0);
  k_packbf<<<dim3(8, 48), tb, 0, stream>>>(enc_wih1, Hz, 0, W8e1, 0);
  k_packbf<<<dim3(8, 48), tb, 0, stream>>>(enc_whh1, Hz, 0, W8e1, 64);
  k_packbf<<<dim3(8, 48), tb, 0, stream>>>(dec_wih0, Ez + Hz, Ez, W8d0x, 0);
  k_packbf<<<dim3(8, 48), tb, 0, stream>>>(dec_whh0, Hz, 0, W8d0h, 0);
  k_packbf<<<dim3(8, 48), tb, 0, stream>>>(dec_wih1, Hz, 0, W8d1x, 0);
  k_packbf<<<dim3(8, 48), tb, 0, stream>>>(dec_whh1, Hz, 0, W8d1h, 0);
  k_transpose<<<dim3(Hz / 32, Hz / 32), tb, 0, stream>>>(attn_w, Hz, Hz, 0, wtAttn);

  hipMemsetAsync(h0buf, 0, (size_t)2 * Bz * Hz * 4, stream);
  hipMemsetAsync(h1buf, 0, (size_t)2 * Bz * Hz * 4, stream);
  hipMemsetAsync(ctxbuf, 0, (size_t)2 * Bz * Hz * 4, stream);
  hipMemsetAsync(d1ctxBf + (size_t)2016 * 1024, 0, (size_t)32 * 1024 * 2, stream);
  hipMemsetAsync(flags, 0, NB * 4, stream);

  k_embed_gi<<<24 * 128, tb, 0, stream>>>(src, enc_emb, W4embE, enc_bih0, giEnc);
  k_embed_gi<<<24 * 126, tb, 0, stream>>>(tgt, dec_emb, W4embD, dec_bih0, giDec);
  k_f2bf<<<2048, tb, 0, stream>>>(out_w, outwBf, (long)Vz * 1024 / 4);

  PP pp;
  pp.giEnc = giEnc; pp.giDec = giDec;
  pp.W8e0 = W8e0; pp.W8e1 = W8e1;
  pp.W8d0x = W8d0x; pp.W8d0h = W8d0h; pp.W8d1x = W8d1x; pp.W8d1h = W8d1h;
  pp.enc_bhh0 = enc_bhh0; pp.enc_bih1 = enc_bih1; pp.enc_bhh1 = enc_bhh1;
  pp.dec_bhh0 = dec_bhh0; pp.dec_bih1 = dec_bih1; pp.dec_bhh1 = dec_bhh1;
  pp.wtAttn = wtAttn; pp.src = src;
  pp.h0 = h0buf; pp.h1 = h1buf; pp.d0 = d0buf; pp.d1 = d1buf; pp.ctx = ctxbuf;
  pp.hpd0 = hpd0; pp.hpd1 = hpd1;
  pp.encOut = encOut; pp.keNb = keNb; pp.encNb = encNb;
  pp.flags = flags; pp.d1ctxBf = d1ctxBf;
  k_persist<<<NB, dim3(512), 0, stream>>>(pp);

  k_out_gemm<<<16 * 250, tb, 0, stream>>>(d1ctxBf, outwBf, out_b, out);
}

// Round 8
// 4092.663 us; speedup vs baseline: 2.7406x; 1.0697x over previous
//
#include <hip/hip_runtime.h>

#define Bz   32
#define Sz   64
#define Tdec 63
#define Ez   256
#define Hz   512
#define H3z  1536
#define Vz   32000
#define NB   128   // persistent grid blocks

typedef __attribute__((ext_vector_type(4))) float f32x4;
typedef __attribute__((ext_vector_type(4))) float floatx4;
typedef __attribute__((ext_vector_type(8))) short shortx8;
typedef __attribute__((ext_vector_type(8))) unsigned short u16x8;

__device__ __forceinline__ unsigned short f2bf(float f) {
  unsigned x = __float_as_uint(f);
  unsigned r = (x + 0x7fffu + ((x >> 16) & 1u)) >> 16;
  return (unsigned short)r;
}
__device__ __forceinline__ float bf2f(unsigned short u) {
  return __uint_as_float((unsigned)u << 16);
}

// ======== sc0/sc1 (MALL-coherent, L1/L2-bypass) access helpers ========
__device__ __forceinline__ f32x4 ld_sc_nw(const f32x4* p) {  // no wait
  f32x4 r;
  asm volatile("global_load_dwordx4 %0, %1, off sc0 sc1" : "=&v"(r) : "v"(p));
  return r;
}
__device__ __forceinline__ float ld1f_sc_nw(const float* p) {  // no wait
  float r;
  asm volatile("global_load_dword %0, %1, off sc0 sc1" : "=&v"(r) : "v"(p));
  return r;
}
__device__ __forceinline__ void wait_vm0() {
  asm volatile("s_waitcnt vmcnt(0)" ::: "memory");
}
__device__ __forceinline__ void ld1f_sc(const float* p, float& a) {
  asm volatile(
      "global_load_dword %0, %1, off sc0 sc1\n\t"
      "s_waitcnt vmcnt(0)"
      : "=&v"(a) : "v"(p) : "memory");
}
__device__ __forceinline__ void st_sc(float* p, float v) {
  asm volatile("global_store_dword %0, %1, off sc0 sc1" :: "v"(p), "v"(v) : "memory");
}
__device__ __forceinline__ void st_flag(unsigned* p, unsigned v) {
  asm volatile("global_store_dword %0, %1, off sc0 sc1" :: "v"(p), "v"(v) : "memory");
}
__device__ __forceinline__ void ld2u_sc(const unsigned* p0, const unsigned* p1,
                                        unsigned& a, unsigned& b) {
  asm volatile(
      "global_load_dword %0, %2, off sc0 sc1\n\t"
      "global_load_dword %1, %3, off sc0 sc1\n\t"
      "s_waitcnt vmcnt(0)"
      : "=&v"(a), "=&v"(b) : "v"(p0), "v"(p1) : "memory");
}
__device__ __forceinline__ void ld1u_sc(const unsigned* p, unsigned& a) {
  asm volatile(
      "global_load_dword %0, %1, off sc0 sc1\n\t"
      "s_waitcnt vmcnt(0)"
      : "=&v"(a) : "v"(p) : "memory");
}

// ---------------- generic transpose: out[c][r] = in[r][c0+c] ----------------
__global__ __launch_bounds__(256)
void k_transpose(const float* __restrict__ in, int R, int Ctot, int c0,
                 float* __restrict__ out) {
  __shared__ float tile[32][33];
  int ct = blockIdx.x * 32;
  int rt = blockIdx.y * 32;
  int lx = threadIdx.x & 31, ly = threadIdx.x >> 5;
#pragma unroll
  for (int i = 0; i < 32; i += 8)
    tile[ly + i][lx] = in[(long)(rt + ly + i) * Ctot + c0 + ct + lx];
  __syncthreads();
#pragma unroll
  for (int i = 0; i < 32; i += 8)
    out[(long)(ct + ly + i) * R + rt + lx] = tile[lx][ly + i];
}

// ---- pack fp32 weights (embed GEMM): out[(k4)*1536*4 + j*4 + q] ----
__global__ __launch_bounds__(256)
void k_pack4(const float* __restrict__ in, int rs, int c0,
             float* __restrict__ out, int k4off) {
  int jl = threadIdx.x & 15, k4l = threadIdx.x >> 4;
  int j = blockIdx.y * 16 + jl;
  int k4 = blockIdx.x * 16 + k4l;
  float4 v = *(const float4*)(in + (long)j * rs + c0 + k4 * 4);
  *(float4*)(out + ((long)(k4 + k4off) * H3z + j) * 4) = v;
}

// ---- pack recurrent weights to bf16: out[(k8+k8off)*1536 + j][8] ----
__global__ __launch_bounds__(256)
void k_packbf(const float* __restrict__ in, int rs, int c0,
              unsigned short* __restrict__ out, int k8off) {
  int jl = threadIdx.x & 31, k8l = threadIdx.x >> 5;  // 32 j x 8 k8
  int j = blockIdx.y * 32 + jl;
  int k8 = blockIdx.x * 8 + k8l;
  const float* src = in + (long)j * rs + c0 + k8 * 8;
  float4 a = *(const float4*)src;
  float4 b = *(const float4*)(src + 4);
  u16x8 o;
  o[0] = f2bf(a.x); o[1] = f2bf(a.y); o[2] = f2bf(a.z); o[3] = f2bf(a.w);
  o[4] = f2bf(b.x); o[5] = f2bf(b.y); o[6] = f2bf(b.z); o[7] = f2bf(b.w);
  *(u16x8*)(out + ((long)(k8 + k8off) * H3z + j) * 8) = o;
}

// -------- embed + input-GEMM with packed fp32 weights W4[k4][1536][4], K=256
__global__ __launch_bounds__(256)
void k_embed_gi(const int* __restrict__ toks, const float* __restrict__ emb,
                const float* __restrict__ W4, const float* __restrict__ bias,
                float* __restrict__ G) {
  __shared__ float se[16][Ez];
  int jg = blockIdx.x % 24;
  int rg = blockIdx.x / 24;
  int r0 = rg * 16;
  int tid = threadIdx.x;
  for (int c = tid; c < 16 * Ez; c += 256) {
    int rl = c >> 8;
    int k = c & 255;
    int r = r0 + rl;
    int tok = toks[(r & 31) * 64 + (r >> 5)];
    se[rl][k] = emb[(long)tok * Ez + k];
  }
  __syncthreads();
  int jj = tid & 63, rq = tid >> 6;
  int j = jg * 64 + jj;
  float a0 = 0.f, a1 = 0.f, a2 = 0.f, a3 = 0.f;
#pragma unroll 4
  for (int k4 = 0; k4 < 64; ++k4) {
    float4 w = *(const float4*)(W4 + ((long)k4 * H3z + j) * 4);
    const float* s0 = &se[rq * 4 + 0][k4 * 4];
    const float* s1 = &se[rq * 4 + 1][k4 * 4];
    const float* s2 = &se[rq * 4 + 2][k4 * 4];
    const float* s3 = &se[rq * 4 + 3][k4 * 4];
    a0 = fmaf(s0[3], w.w, fmaf(s0[2], w.z, fmaf(s0[1], w.y, fmaf(s0[0], w.x, a0))));
    a1 = fmaf(s1[3], w.w, fmaf(s1[2], w.z, fmaf(s1[1], w.y, fmaf(s1[0], w.x, a1))));
    a2 = fmaf(s2[3], w.w, fmaf(s2[2], w.z, fmaf(s2[1], w.y, fmaf(s2[0], w.x, a2))));
    a3 = fmaf(s3[3], w.w, fmaf(s3[2], w.z, fmaf(s3[1], w.y, fmaf(s3[0], w.x, a3))));
  }
  float bj = bias[j];
  G[(long)(r0 + rq * 4 + 0) * H3z + j] = a0 + bj;
  G[(long)(r0 + rq * 4 + 1) * H3z + j] = a1 + bj;
  G[(long)(r0 + rq * 4 + 2) * H3z + j] = a2 + bj;
  G[(long)(r0 + rq * 4 + 3) * H3z + j] = a3 + bj;
}

// ---------------- fp32 -> bf16 convert ----------------
__global__ void k_f2bf(const float* __restrict__ in, unsigned short* __restrict__ out, long n4) {
  long i = (long)blockIdx.x * blockDim.x + threadIdx.x;
  long stride = (long)gridDim.x * blockDim.x;
  for (; i < n4; i += stride) {
    float4 v = ((const float4*)in)[i];
    ushort4 o;
    o.x = f2bf(v.x); o.y = f2bf(v.y); o.z = f2bf(v.z); o.w = f2bf(v.w);
    ((ushort4*)out)[i] = o;
  }
}

// ================= persistent recurrence kernel =================
struct PP {
  const float* giEnc;
  const float* giDec;
  const unsigned short* W8e0;    // [64 k8][1536][8]   enc whh0
  const unsigned short* W8e1;    // [128 k8][1536][8]  enc wih1 | whh1
  const unsigned short* W8d0x;   // [64]  dec wih0 ctx-cols
  const unsigned short* W8d0h;   // [64]  dec whh0
  const unsigned short* W8d1x;   // [64]  dec wih1
  const unsigned short* W8d1h;   // [64]  dec whh1
  const float* enc_bhh0;
  const float* enc_bih1;
  const float* enc_bhh1;
  const float* dec_bhh0;
  const float* dec_bih1;
  const float* dec_bhh1;
  const float* wtAttn;
  const int* src;
  float* h0; float* h1; float* d0; float* d1; float* ctx;  // 2-slot sc state
  float* hpd0; float* hpd1;      // 2-slot [3][32][512] h-part partials (sc)
  float* encOut;                 // sc [32][64][512]
  unsigned short* keNb;          // bf16 [32*64][512] normal-cached
  unsigned short* encNb;         // bf16 [32*64][512] normal-cached
  unsigned* flags;               // [NB] per-block arrival
  unsigned* epoch;               // single word, leader-published
  unsigned short* d1ctxBf;
};

// Epoch leader barrier: each block publishes flags[blk]; block 0 (one wave)
// sweeps all flags then publishes epoch; all others spin 1 lane on 1 dword.
// ~64x less MALL spin traffic than all-blocks-sweep.
__device__ __forceinline__ void gsync(unsigned* flags, unsigned* epoch, unsigned ph) {
  wait_vm0();
  __syncthreads();
  const int tid = threadIdx.x;
  if (tid == 0) st_flag(&flags[blockIdx.x], ph);
  if (blockIdx.x == 0) {
    if (tid < 64) {
      const unsigned* p0 = &flags[tid];
      const unsigned* p1 = &flags[tid + 64];
      for (;;) {
        unsigned f0, f1;
        ld2u_sc(p0, p1, f0, f1);
        if (!__any(f0 < ph || f1 < ph)) break;
        __builtin_amdgcn_s_sleep(1);
      }
      if (tid == 0) st_flag(epoch, ph);
    }
  } else if (tid == 0) {
    unsigned e;
    for (;;) {
      ld1u_sc(epoch, e);
      if (e >= ph) break;
      __builtin_amdgcn_s_sleep(2);
    }
  }
  __syncthreads();
}

// ---- shared weight-pipeline pieces: 8 waves, wave kq owns a k8-row range ----
#define W_PREFETCH_G0(Wr0, wA)                                        \
  { const u16x8* Wr = (Wr0);                                          \
    wA[0][0] = Wr[0];    wA[0][1] = Wr[512];  wA[0][2] = Wr[1024];    \
    wA[1][0] = Wr[1536]; wA[1][1] = Wr[2048]; wA[1][2] = Wr[2560]; }

// full GRU cell (encoder): 8 waves; HASX: waves 0-3 x-part, 4-7 h-part.
template <int HASX>
__device__ __forceinline__ void gru_full(
    int blkid, const unsigned short* __restrict__ W8,
    const float* __restrict__ gi, const float* __restrict__ bih,
    const float* __restrict__ bhh,
    const float* __restrict__ xin, const float* __restrict__ hin,
    float* __restrict__ hout, float* __restrict__ fout, long fstride,
    float* smem) {
  float* sh = smem;
  float* sx = smem + 2048;
  float* part = smem + 4096;
  const int jg = blkid & 7, bg = blkid >> 3;
  const int tid = threadIdx.x;
  const int l = tid & 63, kq = tid >> 6;
  const int j = jg * 64 + l;
  constexpr int Q8 = HASX ? 16 : 8;
  constexpr int G8 = Q8 / 2;
  const u16x8* Wr0 = (const u16x8*)W8 + (long)(kq * Q8) * H3z + j;

  u16x8 wA[2][3], wB[2][3];
  W_PREFETCH_G0(Wr0, wA);
  float gir = 0.f, giz = 0.f, gin = 0.f;
  if (tid < 256) {
    const int b4 = tid >> 6, jc = tid & 63;
    const int b = bg * 4 + b4, jj = jg * 64 + jc;
    if (gi) {
      gir = gi[(long)b * H3z + jj];
      giz = gi[(long)b * H3z + 512 + jj];
      gin = gi[(long)b * H3z + 1024 + jj];
    }
    if (bih) { gir += bih[jj]; giz += bih[512 + jj]; gin += bih[1024 + jj]; }
  }
  {
    const f32x4* hp = (const f32x4*)(hin + bg * 2048);
    f32x4 a = ld_sc_nw(hp + tid);
    if (HASX) {
      const f32x4* xp = (const f32x4*)(xin + bg * 2048);
      f32x4 c = ld_sc_nw(xp + tid);
      wait_vm0();
      ((f32x4*)sh)[tid] = a;
      ((f32x4*)sx)[tid] = c;
    } else {
      wait_vm0();
      ((f32x4*)sh)[tid] = a;
    }
  }
  __syncthreads();
  const float* vb;
  if (HASX) vb = (kq < 4) ? (sx + kq * 128) : (sh + (kq - 4) * 128);
  else      vb = sh + kq * 64;
  float pr[4] = {0, 0, 0, 0}, pz[4] = {0, 0, 0, 0}, pn[4] = {0, 0, 0, 0};
  auto loadg = [&](u16x8 (&w)[2][3], int g) {
    const u16x8* Wr = Wr0 + (long)(2 * g) * H3z;
    w[0][0] = Wr[0];    w[0][1] = Wr[512];  w[0][2] = Wr[1024];
    w[1][0] = Wr[1536]; w[1][1] = Wr[2048]; w[1][2] = Wr[2560];
  };
  auto compg = [&](u16x8 (&w)[2][3], int g) {
#pragma unroll
    for (int r = 0; r < 2; ++r) {
      const int kk = 2 * g + r;
      float f0[8], f1[8], f2[8];
#pragma unroll
      for (int e = 0; e < 8; ++e) {
        f0[e] = bf2f(w[r][0][e]); f1[e] = bf2f(w[r][1][e]); f2[e] = bf2f(w[r][2][e]);
      }
#pragma unroll
      for (int b4 = 0; b4 < 4; ++b4) {
        const float* v = vb + kk * 8 + b4 * 512;
        f32x4 v0 = *(const f32x4*)v;
        f32x4 v1 = *(const f32x4*)(v + 4);
#pragma unroll
        for (int e = 0; e < 4; ++e) {
          pr[b4] = fmaf(v0[e], f0[e], pr[b4]);
          pz[b4] = fmaf(v0[e], f1[e], pz[b4]);
          pn[b4] = fmaf(v0[e], f2[e], pn[b4]);
        }
#pragma unroll
        for (int e = 0; e < 4; ++e) {
          pr[b4] = fmaf(v1[e], f0[4 + e], pr[b4]);
          pz[b4] = fmaf(v1[e], f1[4 + e], pz[b4]);
          pn[b4] = fmaf(v1[e], f2[4 + e], pn[b4]);
        }
      }
    }
  };
#pragma unroll
  for (int g = 0; g < G8; g += 2) {
    if (g + 1 < G8) loadg(wB, g + 1);
    compg(wA, g);
    if (g + 2 < G8) loadg(wA, g + 2);
    if (g + 1 < G8) compg(wB, g + 1);
  }
#pragma unroll
  for (int b4 = 0; b4 < 4; ++b4) {
    part[((0 * 4 + b4) * 8 + kq) * 64 + l] = pr[b4];
    part[((1 * 4 + b4) * 8 + kq) * 64 + l] = pz[b4];
    part[((2 * 4 + b4) * 8 + kq) * 64 + l] = pn[b4];
  }
  __syncthreads();
  if (tid < 256) {
    const int b4 = tid >> 6, jc = tid & 63;
    const int b = bg * 4 + b4;
    const int jj = jg * 64 + jc;
    float sr = 0.f, sz = 0.f, snx = 0.f, snh = 0.f;
#pragma unroll
    for (int q = 0; q < 8; ++q) {
      sr += part[((0 * 4 + b4) * 8 + q) * 64 + jc];
      sz += part[((1 * 4 + b4) * 8 + q) * 64 + jc];
      float pnq = part[((2 * 4 + b4) * 8 + q) * 64 + jc];
      if (HASX && q < 4) snx += pnq; else snh += pnq;
    }
    float rv = 1.f / (1.f + __expf(-(gir + sr + bhh[jj])));
    float zv = 1.f / (1.f + __expf(-(giz + sz + bhh[512 + jj])));
    float nv = tanhf(gin + snx + rv * (snh + bhh[1024 + jj]));
    float hv = sh[b4 * 512 + jj];
    float hp2 = (1.f - zv) * nv + zv * hv;
    st_sc(hout + (long)b * 512 + jj, hp2);
    if (fout) st_sc(fout + (long)b * fstride + jj, hp2);
  }
}

// x-part + combine (decoder): k=512 x-GEMV; h-part partials prefetched early.
__device__ __forceinline__ void gru_xpart(
    int blkid, const unsigned short* __restrict__ Wx,
    const float* __restrict__ gi, const float* __restrict__ bih,
    const float* __restrict__ bhh,
    const float* __restrict__ xin, const float* __restrict__ hprev,
    const float* __restrict__ hp, float* __restrict__ hout,
    unsigned short* __restrict__ bfout, float* smem) {
  float* sx = smem;
  float* part = smem + 4096;
  const int jg = blkid & 7, bg = blkid >> 3;
  const int tid = threadIdx.x;
  const int l = tid & 63, kq = tid >> 6;
  const int j = jg * 64 + l;
  const u16x8* Wr0 = (const u16x8*)Wx + (long)(kq * 8) * H3z + j;
  u16x8 wA[2][3], wB[2][3];
  W_PREFETCH_G0(Wr0, wA);
  float gir = 0.f, giz = 0.f, gin = 0.f;
  float hr = 0.f, hz = 0.f, hn = 0.f, hv = 0.f;
  const int b4c = tid >> 6, jcc = tid & 63;
  const int bc = bg * 4 + b4c, jjc = jg * 64 + jcc;
  if (tid < 256) {
    // issue h-part partial + prev-state sc loads EARLY (ready since last phase)
    hr = ld1f_sc_nw(hp + (long)(0 * 32 + bc) * 512 + jjc);
    hz = ld1f_sc_nw(hp + (long)(1 * 32 + bc) * 512 + jjc);
    hn = ld1f_sc_nw(hp + (long)(2 * 32 + bc) * 512 + jjc);
    hv = ld1f_sc_nw(hprev + (long)bc * 512 + jjc);
    if (gi) {
      gir = gi[(long)bc * H3z + jjc];
      giz = gi[(long)bc * H3z + 512 + jjc];
      gin = gi[(long)bc * H3z + 1024 + jjc];
    }
    if (bih) { gir += bih[jjc]; giz += bih[512 + jjc]; gin += bih[1024 + jjc]; }
  }
  {
    const f32x4* xp = (const f32x4*)(xin + bg * 2048);
    f32x4 a = ld_sc_nw(xp + tid);
    wait_vm0();   // covers the early hp loads too
    ((f32x4*)sx)[tid] = a;
  }
  __syncthreads();
  const float* vb = sx + kq * 64;
  float pr[4] = {0, 0, 0, 0}, pz[4] = {0, 0, 0, 0}, pn[4] = {0, 0, 0, 0};
  auto loadg = [&](u16x8 (&w)[2][3], int g) {
    const u16x8* Wr = Wr0 + (long)(2 * g) * H3z;
    w[0][0] = Wr[0];    w[0][1] = Wr[512];  w[0][2] = Wr[1024];
    w[1][0] = Wr[1536]; w[1][1] = Wr[2048]; w[1][2] = Wr[2560];
  };
  auto compg = [&](u16x8 (&w)[2][3], int g) {
#pragma unroll
    for (int r = 0; r < 2; ++r) {
      const int kk = 2 * g + r;
      float f0[8], f1[8], f2[8];
#pragma unroll
      for (int e = 0; e < 8; ++e) {
        f0[e] = bf2f(w[r][0][e]); f1[e] = bf2f(w[r][1][e]); f2[e] = bf2f(w[r][2][e]);
      }
#pragma unroll
      for (int b4 = 0; b4 < 4; ++b4) {
        const float* v = vb + kk * 8 + b4 * 512;
        f32x4 v0 = *(const f32x4*)v;
        f32x4 v1 = *(const f32x4*)(v + 4);
#pragma unroll
        for (int e = 0; e < 4; ++e) {
          pr[b4] = fmaf(v0[e], f0[e], pr[b4]);
          pz[b4] = fmaf(v0[e], f1[e], pz[b4]);
          pn[b4] = fmaf(v0[e], f2[e], pn[b4]);
        }
#pragma unroll
        for (int e = 0; e < 4; ++e) {
          pr[b4] = fmaf(v1[e], f0[4 + e], pr[b4]);
          pz[b4] = fmaf(v1[e], f1[4 + e], pz[b4]);
          pn[b4] = fmaf(v1[e], f2[4 + e], pn[b4]);
        }
      }
    }
  };
#pragma unroll
  for (int g = 0; g < 4; g += 2) {
    loadg(wB, g + 1);
    compg(wA, g);
    if (g + 2 < 4) loadg(wA, g + 2);
    compg(wB, g + 1);
  }
#pragma unroll
  for (int b4 = 0; b4 < 4; ++b4) {
    part[((0 * 4 + b4) * 8 + kq) * 64 + l] = pr[b4];
    part[((1 * 4 + b4) * 8 + kq) * 64 + l] = pz[b4];
    part[((2 * 4 + b4) * 8 + kq) * 64 + l] = pn[b4];
  }
  __syncthreads();
  if (tid < 256) {
    float sr = 0.f, sz = 0.f, sn = 0.f;
#pragma unroll
    for (int q = 0; q < 8; ++q) {
      sr += part[((0 * 4 + b4c) * 8 + q) * 64 + jcc];
      sz += part[((1 * 4 + b4c) * 8 + q) * 64 + jcc];
      sn += part[((2 * 4 + b4c) * 8 + q) * 64 + jcc];
    }
    float rv = 1.f / (1.f + __expf(-(gir + sr + hr + bhh[jjc])));
    float zv = 1.f / (1.f + __expf(-(giz + sz + hz + bhh[512 + jjc])));
    float nv = tanhf(gin + sn + rv * (hn + bhh[1024 + jjc]));
    float hp2 = (1.f - zv) * nv + zv * hv;
    st_sc(hout + (long)bc * 512 + jjc, hp2);
    if (bfout) bfout[(long)bc * 1024 + jjc] = f2bf(hp2);
  }
}

// h-part producer: hpOut[g][b][jj] = (Whh · hin)[g*512+jj] for batch b (no bias)
__device__ __forceinline__ void gru_hpart(
    int blkid, const unsigned short* __restrict__ Wh,
    const float* __restrict__ hin, float* __restrict__ hpOut, float* smem) {
  float* sh = smem;
  float* part = smem + 4096;
  const int jg = blkid & 7, bg = blkid >> 3;
  const int tid = threadIdx.x;
  const int l = tid & 63, kq = tid >> 6;
  const int j = jg * 64 + l;
  const u16x8* Wr0 = (const u16x8*)Wh + (long)(kq * 8) * H3z + j;
  u16x8 wA[2][3], wB[2][3];
  W_PREFETCH_G0(Wr0, wA);
  {
    const f32x4* hp = (const f32x4*)(hin + bg * 2048);
    f32x4 a = ld_sc_nw(hp + tid);
    wait_vm0();
    ((f32x4*)sh)[tid] = a;
  }
  __syncthreads();
  const float* vb = sh + kq * 64;
  float pr[4] = {0, 0, 0, 0}, pz[4] = {0, 0, 0, 0}, pn[4] = {0, 0, 0, 0};
  auto loadg = [&](u16x8 (&w)[2][3], int g) {
    const u16x8* Wr = Wr0 + (long)(2 * g) * H3z;
    w[0][0] = Wr[0];    w[0][1] = Wr[512];  w[0][2] = Wr[1024];
    w[1][0] = Wr[1536]; w[1][1] = Wr[2048]; w[1][2] = Wr[2560];
  };
  auto compg = [&](u16x8 (&w)[2][3], int g) {
#pragma unroll
    for (int r = 0; r < 2; ++r) {
      const int kk = 2 * g + r;
      float f0[8], f1[8], f2[8];
#pragma unroll
      for (int e = 0; e < 8; ++e) {
        f0[e] = bf2f(w[r][0][e]); f1[e] = bf2f(w[r][1][e]); f2[e] = bf2f(w[r][2][e]);
      }
#pragma unroll
      for (int b4 = 0; b4 < 4; ++b4) {
        const float* v = vb + kk * 8 + b4 * 512;
        f32x4 v0 = *(const f32x4*)v;
        f32x4 v1 = *(const f32x4*)(v + 4);
#pragma unroll
        for (int e = 0; e < 4; ++e) {
          pr[b4] = fmaf(v0[e], f0[e], pr[b4]);
          pz[b4] = fmaf(v0[e], f1[e], pz[b4]);
          pn[b4] = fmaf(v0[e], f2[e], pn[b4]);
        }
#pragma unroll
        for (int e = 0; e < 4; ++e) {
          pr[b4] = fmaf(v1[e], f0[4 + e], pr[b4]);
          pz[b4] = fmaf(v1[e], f1[4 + e], pz[b4]);
          pn[b4] = fmaf(v1[e], f2[4 + e], pn[b4]);
        }
      }
    }
  };
#pragma unroll
  for (int g = 0; g < 4; g += 2) {
    loadg(wB, g + 1);
    compg(wA, g);
    if (g + 2 < 4) loadg(wA, g + 2);
    compg(wB, g + 1);
  }
#pragma unroll
  for (int b4 = 0; b4 < 4; ++b4) {
    part[((0 * 4 + b4) * 8 + kq) * 64 + l] = pr[b4];
    part[((1 * 4 + b4) * 8 + kq) * 64 + l] = pz[b4];
    part[((2 * 4 + b4) * 8 + kq) * 64 + l] = pn[b4];
  }
  __syncthreads();
  if (tid < 256) {
    const int b4 = tid >> 6, jc = tid & 63;
    const int b = bg * 4 + b4;
    const int jj = jg * 64 + jc;
    float s0 = 0.f, s1 = 0.f, s2 = 0.f;
#pragma unroll
    for (int q = 0; q < 8; ++q) {
      s0 += part[((0 * 4 + b4) * 8 + q) * 64 + jc];
      s1 += part[((1 * 4 + b4) * 8 + q) * 64 + jc];
      s2 += part[((2 * 4 + b4) * 8 + q) * 64 + jc];
    }
    st_sc(hpOut + (long)(0 * 32 + b) * 512 + jj, s0);
    st_sc(hpOut + (long)(1 * 32 + b) * 512 + jj, s1);
    st_sc(hpOut + (long)(2 * 32 + b) * 512 + jj, s2);
  }
}

// ke + bf16 republish (512 threads): block (b=blk&31, sq=blk>>5) -> 16 rows
__device__ void ke_phase(int blk, const float* __restrict__ encOut,
                         const float* __restrict__ attn_wT,
                         unsigned short* __restrict__ keNb,
                         unsigned short* __restrict__ encNb, float* smem) {
  int b = blk & 31, sq = blk >> 5;
  long r0 = (long)b * 64 + sq * 16;
  int tid = threadIdx.x;
  {
    const f32x4* ep = (const f32x4*)(encOut + r0 * 512);
    f32x4 v[4];
#pragma unroll
    for (int u = 0; u < 4; ++u) v[u] = ld_sc_nw(ep + tid + u * 512);
    wait_vm0();
#pragma unroll
    for (int u = 0; u < 4; ++u) ((f32x4*)smem)[tid + u * 512] = v[u];
  }
  __syncthreads();
  {
    u16x8 o0, o1;
    const float* s = smem + tid * 16;
#pragma unroll
    for (int e = 0; e < 8; ++e) { o0[e] = f2bf(s[e]); o1[e] = f2bf(s[8 + e]); }
    *(u16x8*)(encNb + r0 * 512 + tid * 16) = o0;
    *(u16x8*)(encNb + r0 * 512 + tid * 16 + 8) = o1;
  }
  int jj = tid & 63, rq = tid >> 6;  // 8 groups x 2 rows
  float acc[2][8];
#pragma unroll
  for (int r = 0; r < 2; ++r)
#pragma unroll
    for (int jc = 0; jc < 8; ++jc) acc[r][jc] = 0.f;
#pragma unroll 2
  for (int k = 0; k < 512; ++k) {
    float w[8];
#pragma unroll
    for (int jc = 0; jc < 8; ++jc) w[jc] = attn_wT[(long)k * 512 + jc * 64 + jj];
    float e0 = smem[(rq * 2) * 512 + k], e1 = smem[(rq * 2 + 1) * 512 + k];
#pragma unroll
    for (int jc = 0; jc < 8; ++jc) {
      acc[0][jc] = fmaf(e0, w[jc], acc[0][jc]);
      acc[1][jc] = fmaf(e1, w[jc], acc[1][jc]);
    }
  }
#pragma unroll
  for (int r = 0; r < 2; ++r)
#pragma unroll
    for (int jc = 0; jc < 8; ++jc)
      keNb[(r0 + rq * 2 + r) * 512 + jc * 64 + jj] = f2bf(acc[r][jc]);
}

__device__ void attn_phase(int b, const float* __restrict__ d1,
                           const unsigned short* __restrict__ keNb,
                           const unsigned short* __restrict__ encNb,
                           const int* __restrict__ src,
                           float* __restrict__ ctxn,
                           unsigned short* __restrict__ bfctx, float* smem) {
  float* sd = smem;
  float* sc = smem + 512;
  int tid = threadIdx.x;
  {
    float a;
    ld1f_sc(d1 + b * 512 + tid, a);
    sd[tid] = a;
  }
  __syncthreads();
  int s = tid >> 3, q = tid & 7;
  const u16x8* kp = (const u16x8*)(keNb + ((long)b * 64 + s) * 512 + q * 64);
  const float* dp = sd + q * 64;
  float p = 0.f;
#pragma unroll
  for (int e = 0; e < 8; ++e) {
    u16x8 kv = kp[e];
#pragma unroll
    for (int i = 0; i < 8; ++i) p = fmaf(bf2f(kv[i]), dp[e * 8 + i], p);
  }
  p += __shfl_xor(p, 1);
  p += __shfl_xor(p, 2);
  p += __shfl_xor(p, 4);
  if (q == 0) sc[s] = (src[b * 64 + s] == 0) ? -1e9f : p;
  __syncthreads();
  if (tid < 64) {
    float v = sc[tid];
    float m = v;
    for (int o = 32; o; o >>= 1) m = fmaxf(m, __shfl_xor(m, o));
    float e = __expf(v - m);
    float sum = e;
    for (int o = 32; o; o >>= 1) sum += __shfl_xor(sum, o);
    sc[tid] = e / sum;
  }
  __syncthreads();
  float a0 = 0.f;
  const unsigned short* er = encNb + (long)b * 64 * 512 + tid;
#pragma unroll 8
  for (int s2 = 0; s2 < 64; ++s2) a0 = fmaf(sc[s2], bf2f(er[(long)s2 * 512]), a0);
  st_sc(ctxn + b * 512 + tid, a0);
  bfctx[b * 1024 + tid] = f2bf(a0);
}

__global__ __launch_bounds__(512, 2) void k_persist(PP P) {
  __shared__ float smem[10240];  // 40KB
  int blk = blockIdx.x;
  unsigned ph = 0;
  // ---- encoder: layer1 pipelined one step behind layer0 ----
  for (int i = 0; i < Sz + 1; ++i) {
    if (blk < 64) {
      if (i < Sz)
        gru_full<0>(blk, P.W8e0, P.giEnc + (long)i * 49152, nullptr, P.enc_bhh0,
                    nullptr, P.h0 + (i & 1) * 16384, P.h0 + ((i + 1) & 1) * 16384,
                    nullptr, 0, smem);
      else  // i == Sz: h0 final sits in slot 0 -> produce hpd0 for t=0
        gru_hpart(blk, P.W8d0h, P.h0, P.hpd0, smem);
    } else if (i >= 1) {
      int t = i - 1;
      gru_full<1>(blk - 64, P.W8e1, nullptr, P.enc_bih1, P.enc_bhh1,
                  P.h0 + (i & 1) * 16384, P.h1 + (t & 1) * 16384,
                  P.h1 + ((t + 1) & 1) * 16384,
                  P.encOut + (long)t * 512, (long)Sz * 512, smem);
    }
    gsync(P.flags, P.epoch, ++ph);
  }
  // ---- ke (bf16 republish) ----
  ke_phase(blk, P.encOut, P.wtAttn, P.keNb, P.encNb, smem);
  gsync(P.flags, P.epoch, ++ph);
  // ---- decoder: gate-split, 3 phases/step ----
  for (int t = 0; t < Tdec; ++t) {
    int cs = t & 1, ps = cs ^ 1;
    const float* d0prev = (t == 0) ? P.h0 : P.d0 + ps * 16384;
    const float* d1prev = (t == 0) ? P.h1 : P.d1 + ps * 16384;
    // P1: d0^t = xpart(ctx^{t-1}) + hpd0^t ; blocks 64+: hpd1^t = Whh1 d1^{t-1}
    if (blk < 64)
      gru_xpart(blk, P.W8d0x, P.giDec + (long)t * 49152, nullptr, P.dec_bhh0,
                P.ctx + ps * 16384, d0prev, P.hpd0 + cs * 49152,
                P.d0 + cs * 16384, nullptr, smem);
    else
      gru_hpart(blk - 64, P.W8d1h, d1prev, P.hpd1 + cs * 49152, smem);
    gsync(P.flags, P.epoch, ++ph);
    // P2: d1^t = xpart(d0^t) + hpd1^t ; blocks 64+: hpd0^{t+1} = Whh0 d0^t
    if (blk < 64)
      gru_xpart(blk, P.W8d1x, nullptr, P.dec_bih1, P.dec_bhh1,
                P.d0 + cs * 16384, d1prev, P.hpd1 + cs * 49152,
                P.d1 + cs * 16384, P.d1ctxBf + (long)t * 32768, smem);
    else
      gru_hpart(blk - 64, P.W8d0h, P.d0 + cs * 16384, P.hpd0 + ps * 49152, smem);
    gsync(P.flags, P.epoch, ++ph);
    // P3: attention
    if (blk < 32)
      attn_phase(blk, P.d1 + cs * 16384, P.keNb, P.encNb, P.src,
                 P.ctx + cs * 16384, P.d1ctxBf + (long)t * 32768 + 512, smem);
    gsync(P.flags, P.epoch, ++ph);
  }
}

// ---------------- final bf16 MFMA GEMM (validated) ----------------
__global__ __launch_bounds__(256)
void k_out_gemm(const unsigned short* __restrict__ A, const unsigned short* __restrict__ Bw,
                const float* __restrict__ bias, float* __restrict__ out) {
  __shared__ __align__(16) char lds[32768];
  int bid = blockIdx.x;
  int bm = bid & 15, bn = bid >> 4;
  long m0 = (long)bm * 128, n0 = (long)bn * 128;
  int tid = threadIdx.x, lane = tid & 63, wid = tid >> 6;
  int wm = wid >> 1, wn = wid & 1;
  floatx4 acc[4][4];
#pragma unroll
  for (int i = 0; i < 4; i++)
#pragma unroll
    for (int jx = 0; jx < 4; jx++) acc[i][jx] = (floatx4){0.f, 0.f, 0.f, 0.f};

  int rl = lane >> 3;
  int kb = (((lane & 7) ^ rl) << 4);

  for (int kt = 0; kt < 16; ++kt) {
    long kbyte0 = (long)kt * 128;
#pragma unroll
    for (int q = 0; q < 4; ++q) {
      int c = wid * 4 + q;
      int row = c * 8 + rl;
      const char* ga = (const char*)A + (m0 + row) * 2048 + kbyte0 + kb;
      const char* gb = (const char*)Bw + (n0 + row) * 2048 + kbyte0 + kb;
      __builtin_amdgcn_global_load_lds(
          (const __attribute__((address_space(1))) void*)ga,
          (__attribute__((address_space(3))) void*)(lds + (c << 10)), 16, 0, 0);
      __builtin_amdgcn_global_load_lds(
          (const __attribute__((address_space(1))) void*)gb,
          (__attribute__((address_space(3))) void*)(lds + 16384 + (c << 10)), 16, 0, 0);
    }
    asm volatile("s_waitcnt vmcnt(0)" ::: "memory");
    __syncthreads();
#pragma unroll
    for (int kk = 0; kk < 2; ++kk) {
      shortx8 af[4], bf[4];
#pragma unroll
      for (int f = 0; f < 4; ++f) {
        int rowA = wm * 64 + f * 16 + (lane & 15);
        int cbA = (kk * 64 + ((lane >> 4) << 4)) ^ ((rowA & 7) << 4);
        af[f] = *(const shortx8*)(lds + rowA * 128 + cbA);
        int rowB = wn * 64 + f * 16 + (lane & 15);
        int cbB = (kk * 64 + ((lane >> 4) << 4)) ^ ((rowB & 7) << 4);
        bf[f] = *(const shortx8*)(lds + 16384 + rowB * 128 + cbB);
      }
#pragma unroll
      for (int mf = 0; mf < 4; ++mf)
#pragma unroll
        for (int nf = 0; nf < 4; ++nf)
          acc[mf][nf] = __builtin_amdgcn_mfma_f32_16x16x32_bf16(af[mf], bf[nf], acc[mf][nf], 0, 0, 0);
    }
    __syncthreads();
  }
#pragma unroll
  for (int mf = 0; mf < 4; ++mf) {
#pragma unroll
    for (int nf = 0; nf < 4; ++nf) {
      long gn = n0 + wn * 64 + nf * 16 + (lane & 15);
      float bb = bias[gn];
#pragma unroll
      for (int r = 0; r < 4; ++r) {
        long gm = m0 + wm * 64 + mf * 16 + ((lane >> 4) * 4) + r;
        if (gm < (long)Tdec * Bz) {
          long t = gm >> 5, b = gm & 31;
          out[(b * Tdec + t) * (long)Vz + gn] = acc[mf][nf][r] + bb;
        }
      }
    }
  }
}

extern "C" void kernel_launch(void* const* d_in, const int* in_sizes, int n_in,
                              void* d_out, int out_size, void* d_ws, size_t ws_size,
                              hipStream_t stream) {
  const int*   src      = (const int*)d_in[0];
  const int*   tgt      = (const int*)d_in[1];
  const float* enc_emb  = (const float*)d_in[2];
  const float* enc_wih0 = (const float*)d_in[3];
  const float* enc_whh0 = (const float*)d_in[4];
  const float* enc_bih0 = (const float*)d_in[5];
  const float* enc_bhh0 = (const float*)d_in[6];
  const float* enc_wih1 = (const float*)d_in[7];
  const float* enc_whh1 = (const float*)d_in[8];
  const float* enc_bih1 = (const float*)d_in[9];
  const float* enc_bhh1 = (const float*)d_in[10];
  const float* dec_emb  = (const float*)d_in[11];
  const float* dec_wih0 = (const float*)d_in[12];
  const float* dec_whh0 = (const float*)d_in[13];
  const float* dec_bih0 = (const float*)d_in[14];
  const float* dec_bhh0 = (const float*)d_in[15];
  const float* dec_wih1 = (const float*)d_in[16];
  const float* dec_whh1 = (const float*)d_in[17];
  const float* dec_bih1 = (const float*)d_in[18];
  const float* dec_bhh1 = (const float*)d_in[19];
  const float* attn_w   = (const float*)d_in[20];
  const float* out_w    = (const float*)d_in[21];
  const float* out_b    = (const float*)d_in[22];
  float* out = (float*)d_out;

  char* ws = (char*)d_ws;
  size_t off = 0;
  auto alloc = [&](size_t bytes) -> char* {
    char* p = ws + off;
    off += (bytes + 255) & ~(size_t)255;
    return p;
  };
  float* W4embE = (float*)alloc((size_t)Ez * H3z * 4);
  float* W4embD = (float*)alloc((size_t)Ez * H3z * 4);
  unsigned short* W8e0  = (unsigned short*)alloc((size_t)64 * H3z * 8 * 2);
  unsigned short* W8e1  = (unsigned short*)alloc((size_t)128 * H3z * 8 * 2);
  unsigned short* W8d0x = (unsigned short*)alloc((size_t)64 * H3z * 8 * 2);
  unsigned short* W8d0h = (unsigned short*)alloc((size_t)64 * H3z * 8 * 2);
  unsigned short* W8d1x = (unsigned short*)alloc((size_t)64 * H3z * 8 * 2);
  unsigned short* W8d1h = (unsigned short*)alloc((size_t)64 * H3z * 8 * 2);
  float* wtAttn = (float*)alloc((size_t)Hz * Hz * 4);
  float* giEnc  = (float*)alloc((size_t)Sz * Bz * H3z * 4);
  float* giDec  = (float*)alloc((size_t)Tdec * Bz * H3z * 4);
  float* encOut = (float*)alloc((size_t)Bz * Sz * Hz * 4);
  unsigned short* keNb  = (unsigned short*)alloc((size_t)Bz * Sz * Hz * 2);
  unsigned short* encNb = (unsigned short*)alloc((size_t)Bz * Sz * Hz * 2);
  float* h0buf  = (float*)alloc((size_t)2 * Bz * Hz * 4);
  float* h1buf  = (float*)alloc((size_t)2 * Bz * Hz * 4);
  float* d0buf  = (float*)alloc((size_t)2 * Bz * Hz * 4);
  float* d1buf  = (float*)alloc((size_t)2 * Bz * Hz * 4);
  float* ctxbuf = (float*)alloc((size_t)2 * Bz * Hz * 4);
  float* hpd0   = (float*)alloc((size_t)2 * 3 * Bz * Hz * 4);
  float* hpd1   = (float*)alloc((size_t)2 * 3 * Bz * Hz * 4);
  unsigned short* d1ctxBf = (unsigned short*)alloc((size_t)2048 * 1024 * 2);
  unsigned short* outwBf  = (unsigned short*)alloc((size_t)Vz * 1024 * 2);
  unsigned* flags = (unsigned*)alloc(NB * 4);
  unsigned* epoch = (unsigned*)alloc(256);
  if (off > ws_size) return;

  dim3 tb(256);
  k_pack4<<<dim3(4, 96), tb, 0, stream>>>(enc_wih0, Ez, 0, W4embE, 0);
  k_pack4<<<dim3(4, 96), tb, 0, stream>>>(dec_wih0, Ez + Hz, 0, W4embD, 0);
  k_packbf<<<dim3(8, 48), tb, 0, stream>>>(enc_whh0, Hz, 0, W8e0, 0);
  k_packbf<<<dim3(8, 48), tb, 0, stream>>>(enc_wih1, Hz, 0, W8e1, 0);
  k_packbf<<<dim3(8, 48), tb, 0, stream>>>(enc_whh1, Hz, 0, W8e1, 64);
  k_packbf<<<dim3(8, 48), tb, 0, stream>>>(dec_wih0, Ez + Hz, Ez, W8d0x, 0);
  k_packbf<<<dim3(8, 48), tb, 0, stream>>>(dec_whh0, Hz, 0, W8d0h, 0);
  k_packbf<<<dim3(8, 48), tb, 0, stream>>>(dec_wih1, Hz, 0, W8d1x, 0);
  k_packbf<<<dim3(8, 48), tb, 0, stream>>>(dec_whh1, Hz, 0, W8d1h, 0);
  k_transpose<<<dim3(Hz / 32, Hz / 32), tb, 0, stream>>>(attn_w, Hz, Hz, 0, wtAttn);

  hipMemsetAsync(h0buf, 0, (size_t)2 * Bz * Hz * 4, stream);
  hipMemsetAsync(h1buf, 0, (size_t)2 * Bz * Hz * 4, stream);
  hipMemsetAsync(ctxbuf, 0, (size_t)2 * Bz * Hz * 4, stream);
  hipMemsetAsync(d1ctxBf + (size_t)2016 * 1024, 0, (size_t)32 * 1024 * 2, stream);
  hipMemsetAsync(flags, 0, NB * 4, stream);
  hipMemsetAsync(epoch, 0, 256, stream);

  k_embed_gi<<<24 * 128, tb, 0, stream>>>(src, enc_emb, W4embE, enc_bih0, giEnc);
  k_embed_gi<<<24 * 126, tb, 0, stream>>>(tgt, dec_emb, W4embD, dec_bih0, giDec);
  k_f2bf<<<2048, tb, 0, stream>>>(out_w, outwBf, (long)Vz * 1024 / 4);

  PP pp;
  pp.giEnc = giEnc; pp.giDec = giDec;
  pp.W8e0 = W8e0; pp.W8e1 = W8e1;
  pp.W8d0x = W8d0x; pp.W8d0h = W8d0h; pp.W8d1x = W8d1x; pp.W8d1h = W8d1h;
  pp.enc_bhh0 = enc_bhh0; pp.enc_bih1 = enc_bih1; pp.enc_bhh1 = enc_bhh1;
  pp.dec_bhh0 = dec_bhh0; pp.dec_bih1 = dec_bih1; pp.dec_bhh1 = dec_bhh1;
  pp.wtAttn = wtAttn; pp.src = src;
  pp.h0 = h0buf; pp.h1 = h1buf; pp.d0 = d0buf; pp.d1 = d1buf; pp.ctx = ctxbuf;
  pp.hpd0 = hpd0; pp.hpd1 = hpd1;
  pp.encOut = encOut; pp.keNb = keNb; pp.encNb = encNb;
  pp.flags = flags; pp.epoch = epoch; pp.d1ctxBf = d1ctxBf;
  k_persist<<<NB, dim3(512), 0, stream>>>(pp);

  k_out_gemm<<<16 * 250, tb, 0, stream>>>(d1ctxBf, outwBf, out_b, out);
}